// Round 1
// baseline (1405.080 us; speedup 1.0000x reference)
//
#include <hip/hip_runtime.h>
#include <hip/hip_fp16.h>

// MoE top-2, T=16384 tokens, D=1024, H=2048, E=8. All inputs fp32.
// Pipeline: router(top2+x->f16) -> scan -> build lists (+inverse map) ->
// transpose-cvt weights -> grouped GEMM1 (gate+up fused, SiLU) ->
// grouped GEMM2 (down, scaled f16 row store) -> combine (out = y[r0]+y[r1]).
// Internal compute f16 MFMA (16x16x32), fp32 accumulate. Router kept fp32.
// R3: GEMMs restructured to 8-wave BM=256 tiles with triple-buffered LDS
// (144KB), depth-2 prefetch, counted s_waitcnt vmcnt(6) (never drained in
// the main loop), 2 phases per K-tile with setprio(1) around MFMA clusters.
// (T3+T4+T5 from the verified 8-phase template; T2 XOR swizzle kept.)

#define T_TOK 16384
#define EMB_D 1024
#define HID_D 2048
#define NEXP  8
#define LIST_CAP (2 * T_TOK + 256)

typedef _Float16 f16x8 __attribute__((ext_vector_type(8)));
typedef float    f32x4 __attribute__((ext_vector_type(4)));

// async global->LDS, 16B per lane, lane i lands at ldsbase + i*16B
#define GLD16(gp, lp)                                                          \
  __builtin_amdgcn_global_load_lds(                                            \
      (__attribute__((address_space(1))) void*)(void*)(gp),                    \
      (__attribute__((address_space(3))) void*)(lp), 16, 0, 0)

#define VMW(N) asm volatile("s_waitcnt vmcnt(" #N ")" ::: "memory")
#define BARRIER()                                                              \
  do {                                                                         \
    __builtin_amdgcn_sched_barrier(0);                                         \
    __builtin_amdgcn_s_barrier();                                              \
    __builtin_amdgcn_sched_barrier(0);                                         \
  } while (0)

// ---------------------------------------------------------------- router ----
__global__ __launch_bounds__(256) void router_kernel(
    const float* __restrict__ x, const float* __restrict__ rw,
    _Float16* __restrict__ xh, int* __restrict__ top_idx,
    float2* __restrict__ top_w, int* __restrict__ counts) {
  int wave = threadIdx.x >> 6, lane = threadIdx.x & 63;
  int t = blockIdx.x * 4 + wave;              // one wave per token
  const float* xr = x + (size_t)t * EMB_D;
  int d0 = lane * 16;

  float xv[16];
#pragma unroll
  for (int j = 0; j < 4; j++) {
    float4 v = *(const float4*)(xr + d0 + j * 4);
    xv[j * 4 + 0] = v.x; xv[j * 4 + 1] = v.y;
    xv[j * 4 + 2] = v.z; xv[j * 4 + 3] = v.w;
  }
  // fused fp32 -> f16 conversion of x
  _Float16 hx[16];
#pragma unroll
  for (int j = 0; j < 16; j++) hx[j] = (_Float16)xv[j];
  *(f16x8*)(xh + (size_t)t * EMB_D + d0)     = *(f16x8*)(hx);
  *(f16x8*)(xh + (size_t)t * EMB_D + d0 + 8) = *(f16x8*)(hx + 8);

  // logits in fp32 (selection must be exact-ish)
  float acc[NEXP];
#pragma unroll
  for (int e = 0; e < NEXP; e++) acc[e] = 0.f;
#pragma unroll
  for (int j = 0; j < 16; j++) {
    const float* wr = rw + (size_t)(d0 + j) * NEXP;
    float4 wa = *(const float4*)(wr);
    float4 wb = *(const float4*)(wr + 4);
    float xj = xv[j];
    acc[0] += xj * wa.x; acc[1] += xj * wa.y; acc[2] += xj * wa.z; acc[3] += xj * wa.w;
    acc[4] += xj * wb.x; acc[5] += xj * wb.y; acc[6] += xj * wb.z; acc[7] += xj * wb.w;
  }
#pragma unroll
  for (int off = 32; off > 0; off >>= 1)
#pragma unroll
    for (int e = 0; e < NEXP; e++) acc[e] += __shfl_xor(acc[e], off, 64);

  if (lane == 0) {
    int i0 = 0; float v0 = acc[0];
#pragma unroll
    for (int e = 1; e < NEXP; e++) if (acc[e] > v0) { v0 = acc[e]; i0 = e; }
    int i1 = (i0 == 0) ? 1 : 0; float v1 = acc[i1];
#pragma unroll
    for (int e = 0; e < NEXP; e++)
      if (e != i0 && acc[e] > v1) { v1 = acc[e]; i1 = e; }
    float p = __expf(v1 - v0);          // v1 <= v0
    float inv = 1.f / (1.f + p);
    top_idx[t] = i0 | (i1 << 16);
    top_w[t] = make_float2(inv, p * inv);
    atomicAdd(&counts[i0], 1);
    atomicAdd(&counts[i1], 1);
  }
}

// ------------------------------------------------------------------ scan ----
__global__ void scan_kernel(const int* __restrict__ counts,
                            int* __restrict__ offsets, int* __restrict__ cursor) {
  if (threadIdx.x == 0) {
    int s = 0;
    for (int e = 0; e < NEXP; e++) { offsets[e] = s; s += counts[e]; }
  }
  if (threadIdx.x < NEXP) cursor[threadIdx.x] = 0;
}

// ----------------------------------------------------------------- build ----
__global__ __launch_bounds__(256) void build_kernel(
    const int* __restrict__ top_idx, const float2* __restrict__ top_w,
    const int* __restrict__ offsets, int* cursor,
    int* __restrict__ list_token, float* __restrict__ list_w,
    int2* __restrict__ rows) {
  int t = blockIdx.x * 256 + threadIdx.x;
  if (t >= T_TOK) return;
  int pk = top_idx[t];
  float2 w = top_w[t];
  int e0 = pk & 0xffff, e1 = pk >> 16;
  int r0 = offsets[e0] + atomicAdd(&cursor[e0], 1);
  list_token[r0] = t; list_w[r0] = w.x;
  int r1 = offsets[e1] + atomicAdd(&cursor[e1], 1);
  list_token[r1] = t; list_w[r1] = w.y;
  rows[t] = make_int2(r0, r1);
}

// ---------------------------------------------------- weight transpose ------
// src fp32 [mat][R][C] -> dst f16 [mat][C][R]   (B^T layout for the GEMMs)
__global__ __launch_bounds__(256) void transpose_cvt(
    const float* __restrict__ src, _Float16* __restrict__ dst, int R, int C) {
  __shared__ float tile[32][33];
  size_t mb = (size_t)blockIdx.z * R * C;
  src += mb; dst += mb;
  int c0 = blockIdx.x * 32, r0 = blockIdx.y * 32;
  int tx = threadIdx.x & 31, ty = threadIdx.x >> 5;   // ty: 0..7
#pragma unroll
  for (int j = 0; j < 4; j++)
    tile[ty + j * 8][tx] = src[(size_t)(r0 + ty + j * 8) * C + c0 + tx];
  __syncthreads();
#pragma unroll
  for (int j = 0; j < 4; j++)
    dst[(size_t)(c0 + ty + j * 8) * R + r0 + tx] = (_Float16)tile[tx][ty + j * 8];
}

// ----------------------------------------------------------------- GEMM1 ----
// per expert: h = silu(X Wg) * (X Wu), X gathered rows of xh.
// 8 waves. tile M=256 (tokens) x N=64 (hid) x BK=64, both matrices.
// Triple-buffered LDS (144KB), depth-2 prefetch, counted vmcnt, 2 phases/tile.
// LDS XOR swizzle: logical chunk c (8 halves) of row r stored at phys c^(r&7).
__global__ __launch_bounds__(512) void gemm1_kernel(
    const _Float16* __restrict__ xh, const _Float16* __restrict__ wg_t,
    const _Float16* __restrict__ wu_t, const int* __restrict__ counts,
    const int* __restrict__ offsets, const int* __restrict__ list_token,
    _Float16* __restrict__ h) {
  int e = blockIdx.z;
  int Ne = counts[e];
  int m0 = blockIdx.y * 256;
  if (m0 >= Ne) return;
  int n0 = blockIdx.x * 64;
  int base = offsets[e];

  __shared__ _Float16 lds_a[3][256 * 64];   // 96 KB
  __shared__ _Float16 lds_bg[3][64 * 64];   // 24 KB
  __shared__ _Float16 lds_bu[3][64 * 64];   // 24 KB

  int wave = threadIdx.x >> 6, lane = threadIdx.x & 63;
  int lsub = lane >> 3;                 // row within 8-row group
  int chunk = (lane & 7) ^ lsub;        // logical chunk this lane fetches

  const _Float16* ap[4];
#pragma unroll
  for (int j = 0; j < 4; j++) {
    int lr = j * 64 + wave * 8 + lsub;
    int gidx = base + m0 + lr;
    gidx = min(gidx, 2 * T_TOK - 1);                  // pad-row clamp
    int tok = list_token[gidx] & (T_TOK - 1);         // safety mask
    ap[j] = xh + (size_t)tok * EMB_D + chunk * 8;
  }
  int nr = n0 + wave * 8 + lsub;
  const _Float16* bgp = wg_t + ((size_t)e * HID_D + nr) * EMB_D + chunk * 8;
  const _Float16* bup = wu_t + ((size_t)e * HID_D + nr) * EMB_D + chunk * 8;

  // stage unit 0: A rows 0..191 (3 GLD/thread); unit 1: A rows 192..255 + Bg + Bu
  auto stage_u0 = [&](int t, int b) {
#pragma unroll
    for (int j = 0; j < 3; j++)
      GLD16(ap[j] + t * 64, &lds_a[b][(j * 64 + wave * 8) * 64]);
  };
  auto stage_u1 = [&](int t, int b) {
    GLD16(ap[3] + t * 64, &lds_a[b][(192 + wave * 8) * 64]);
    GLD16(bgp + t * 64, &lds_bg[b][(wave * 8) * 64]);
    GLD16(bup + t * 64, &lds_bu[b][(wave * 8) * 64]);
  };

  f32x4 accg[4][2], accu[4][2];
#pragma unroll
  for (int im = 0; im < 4; im++)
#pragma unroll
    for (int in = 0; in < 2; in++) {
      accg[im][in] = (f32x4){0.f, 0.f, 0.f, 0.f};
      accu[im][in] = (f32x4){0.f, 0.f, 0.f, 0.f};
    }

  int wm = (wave >> 1) * 64, wn = (wave & 1) * 32;
  int frow = lane & 15, fquad = lane >> 4;
  int r7 = frow & 7;

  // prologue: prefetch tiles 0 and 1
  stage_u0(0, 0); stage_u1(0, 0);
  stage_u0(1, 1); stage_u1(1, 1);
  VMW(6);                               // tile 0 complete (tile 1 in flight)
  BARRIER();

  int bC = 0;
  for (int t = 0; t < 16; ++t) {
    int bS = bC + 2; if (bS >= 3) bS -= 3;
    // ---------------- phase 0 (ks = 0) ----------------
    {
      int c = fquad;
      int sw = ((c ^ r7) << 3);
      f16x8 af[4], bgf[2], bff[2];
#pragma unroll
      for (int im = 0; im < 4; im++)
        af[im] = *(const f16x8*)&lds_a[bC][(wm + im * 16 + frow) * 64 + sw];
#pragma unroll
      for (int in = 0; in < 2; in++) {
        bgf[in] = *(const f16x8*)&lds_bg[bC][(wn + in * 16 + frow) * 64 + sw];
        bff[in] = *(const f16x8*)&lds_bu[bC][(wn + in * 16 + frow) * 64 + sw];
      }
      if (t < 14) stage_u0(t + 2, bS);
      BARRIER();
      __builtin_amdgcn_s_setprio(1);
#pragma unroll
      for (int im = 0; im < 4; im++)
#pragma unroll
        for (int in = 0; in < 2; in++) {
          accg[im][in] = __builtin_amdgcn_mfma_f32_16x16x32_f16(
              af[im], bgf[in], accg[im][in], 0, 0, 0);
          accu[im][in] = __builtin_amdgcn_mfma_f32_16x16x32_f16(
              af[im], bff[in], accu[im][in], 0, 0, 0);
        }
      __builtin_amdgcn_s_setprio(0);
      BARRIER();
    }
    // ---------------- phase 1 (ks = 1) ----------------
    {
      int c = 4 + fquad;
      int sw = ((c ^ r7) << 3);
      f16x8 af[4], bgf[2], bff[2];
#pragma unroll
      for (int im = 0; im < 4; im++)
        af[im] = *(const f16x8*)&lds_a[bC][(wm + im * 16 + frow) * 64 + sw];
#pragma unroll
      for (int in = 0; in < 2; in++) {
        bgf[in] = *(const f16x8*)&lds_bg[bC][(wn + in * 16 + frow) * 64 + sw];
        bff[in] = *(const f16x8*)&lds_bu[bC][(wn + in * 16 + frow) * 64 + sw];
      }
      if (t < 14) {
        stage_u1(t + 2, bS);
        VMW(6);                         // tile t+1 complete, t+2 in flight
      } else if (t == 14) {
        VMW(0);                         // last tile (15) complete
      }
      BARRIER();
      __builtin_amdgcn_s_setprio(1);
#pragma unroll
      for (int im = 0; im < 4; im++)
#pragma unroll
        for (int in = 0; in < 2; in++) {
          accg[im][in] = __builtin_amdgcn_mfma_f32_16x16x32_f16(
              af[im], bgf[in], accg[im][in], 0, 0, 0);
          accu[im][in] = __builtin_amdgcn_mfma_f32_16x16x32_f16(
              af[im], bff[in], accu[im][in], 0, 0, 0);
        }
      __builtin_amdgcn_s_setprio(0);
      BARRIER();
    }
    bC++; if (bC >= 3) bC -= 3;
  }

#pragma unroll
  for (int im = 0; im < 4; im++)
#pragma unroll
    for (int in = 0; in < 2; in++)
#pragma unroll
      for (int r = 0; r < 4; r++) {
        int lm = m0 + wm + im * 16 + fquad * 4 + r;
        if (lm < Ne) {
          int col = n0 + wn + in * 16 + frow;
          float g = accg[im][in][r], u = accu[im][in][r];
          float hv = (g / (1.f + __expf(-g))) * u;    // silu(g)*u
          h[(size_t)(base + lm) * HID_D + col] = (_Float16)hv;
        }
      }
}

// ----------------------------------------------------------------- GEMM2 ----
// y[list_row] = w * (h_row @ Wd)  (f16 store; no atomics).
// 8 waves. tile 256x128, BK=64, triple-buffered LDS (144KB), counted vmcnt.
__global__ __launch_bounds__(512) void gemm2_kernel(
    const _Float16* __restrict__ h, const _Float16* __restrict__ wd_t,
    const int* __restrict__ counts, const int* __restrict__ offsets,
    const float* __restrict__ list_w, _Float16* __restrict__ y) {
  int e = blockIdx.z;
  int Ne = counts[e];
  int m0 = blockIdx.y * 256;
  if (m0 >= Ne) return;
  int n0 = blockIdx.x * 128;
  int base = offsets[e];

  __shared__ _Float16 lds_a[3][256 * 64];   // 96 KB
  __shared__ _Float16 lds_b[3][128 * 64];   // 48 KB

  int wave = threadIdx.x >> 6, lane = threadIdx.x & 63;
  int lsub = lane >> 3;
  int chunk = (lane & 7) ^ lsub;

  const _Float16* ap[4]; const _Float16* bp[2];
#pragma unroll
  for (int j = 0; j < 4; j++) {
    int lr = j * 64 + wave * 8 + lsub;
    ap[j] = h + (size_t)(base + m0 + lr) * HID_D + chunk * 8;  // LIST_CAP slack covers pad
  }
#pragma unroll
  for (int j = 0; j < 2; j++) {
    int nrr = n0 + j * 64 + wave * 8 + lsub;
    bp[j] = wd_t + ((size_t)e * EMB_D + nrr) * HID_D + chunk * 8;
  }

  auto stage_u0 = [&](int t, int b) {
#pragma unroll
    for (int j = 0; j < 3; j++)
      GLD16(ap[j] + t * 64, &lds_a[b][(j * 64 + wave * 8) * 64]);
  };
  auto stage_u1 = [&](int t, int b) {
    GLD16(ap[3] + t * 64, &lds_a[b][(192 + wave * 8) * 64]);
#pragma unroll
    for (int j = 0; j < 2; j++)
      GLD16(bp[j] + t * 64, &lds_b[b][(j * 64 + wave * 8) * 64]);
  };

  f32x4 acc[4][4];
#pragma unroll
  for (int im = 0; im < 4; im++)
#pragma unroll
    for (int in = 0; in < 4; in++) acc[im][in] = (f32x4){0.f, 0.f, 0.f, 0.f};

  int wm = (wave >> 1) * 64, wn = (wave & 1) * 64;
  int frow = lane & 15, fquad = lane >> 4;
  int r7 = frow & 7;

  stage_u0(0, 0); stage_u1(0, 0);
  stage_u0(1, 1); stage_u1(1, 1);
  VMW(6);
  BARRIER();

  int bC = 0;
  for (int t = 0; t < 32; ++t) {
    int bS = bC + 2; if (bS >= 3) bS -= 3;
    // ---------------- phase 0 (ks = 0) ----------------
    {
      int c = fquad;
      int sw = ((c ^ r7) << 3);
      f16x8 af[4], bf[4];
#pragma unroll
      for (int im = 0; im < 4; im++)
        af[im] = *(const f16x8*)&lds_a[bC][(wm + im * 16 + frow) * 64 + sw];
#pragma unroll
      for (int in = 0; in < 4; in++)
        bf[in] = *(const f16x8*)&lds_b[bC][(wn + in * 16 + frow) * 64 + sw];
      if (t < 30) stage_u0(t + 2, bS);
      BARRIER();
      __builtin_amdgcn_s_setprio(1);
#pragma unroll
      for (int im = 0; im < 4; im++)
#pragma unroll
        for (int in = 0; in < 4; in++)
          acc[im][in] = __builtin_amdgcn_mfma_f32_16x16x32_f16(
              af[im], bf[in], acc[im][in], 0, 0, 0);
      __builtin_amdgcn_s_setprio(0);
      BARRIER();
    }
    // ---------------- phase 1 (ks = 1) ----------------
    {
      int c = 4 + fquad;
      int sw = ((c ^ r7) << 3);
      f16x8 af[4], bf[4];
#pragma unroll
      for (int im = 0; im < 4; im++)
        af[im] = *(const f16x8*)&lds_a[bC][(wm + im * 16 + frow) * 64 + sw];
#pragma unroll
      for (int in = 0; in < 4; in++)
        bf[in] = *(const f16x8*)&lds_b[bC][(wn + in * 16 + frow) * 64 + sw];
      if (t < 30) {
        stage_u1(t + 2, bS);
        VMW(6);
      } else if (t == 30) {
        VMW(0);
      }
      BARRIER();
      __builtin_amdgcn_s_setprio(1);
#pragma unroll
      for (int im = 0; im < 4; im++)
#pragma unroll
        for (int in = 0; in < 4; in++)
          acc[im][in] = __builtin_amdgcn_mfma_f32_16x16x32_f16(
              af[im], bf[in], acc[im][in], 0, 0, 0);
      __builtin_amdgcn_s_setprio(0);
      BARRIER();
    }
    bC++; if (bC >= 3) bC -= 3;
  }

#pragma unroll
  for (int im = 0; im < 4; im++)
#pragma unroll
    for (int r = 0; r < 4; r++) {
      int lm = m0 + wm + im * 16 + fquad * 4 + r;
      if (lm < Ne) {
        int gi = base + lm;
        float w = list_w[gi];
#pragma unroll
        for (int in = 0; in < 4; in++) {
          int col = n0 + wn + in * 16 + frow;
          y[(size_t)gi * EMB_D + col] = (_Float16)(acc[im][in][r] * w);
        }
      }
    }
}

// --------------------------------------------------------------- combine ----
// out[t] = y[r0(t)] + y[r1(t)]   (fp32 out; y rows already weight-scaled)
__global__ __launch_bounds__(256) void combine_kernel(
    const _Float16* __restrict__ y, const int2* __restrict__ rows,
    float* __restrict__ out) {
  int tid = blockIdx.x * 256 + threadIdx.x;   // T*128 threads, 8 elems each
  int t = tid >> 7;
  int d0 = (tid & 127) * 8;
  int2 r = rows[t];
  f16x8 a = *(const f16x8*)(y + (size_t)r.x * EMB_D + d0);
  f16x8 b = *(const f16x8*)(y + (size_t)r.y * EMB_D + d0);
  float o[8];
#pragma unroll
  for (int j = 0; j < 8; j++) o[j] = (float)a[j] + (float)b[j];
  float* op = out + (size_t)t * EMB_D + d0;
  *(float4*)(op)     = make_float4(o[0], o[1], o[2], o[3]);
  *(float4*)(op + 4) = make_float4(o[4], o[5], o[6], o[7]);
}

// ---------------------------------------------------------------- launch ----
extern "C" void kernel_launch(void* const* d_in, const int* in_sizes, int n_in,
                              void* d_out, int out_size, void* d_ws, size_t ws_size,
                              hipStream_t stream) {
  const float* x  = (const float*)d_in[0];
  const float* rw = (const float*)d_in[1];
  const float* wg = (const float*)d_in[2];
  const float* wu = (const float*)d_in[3];
  const float* wd = (const float*)d_in[4];
  float* out = (float*)d_out;

  char* ws = (char*)d_ws;
  size_t off = 0;
  auto alloc = [&](size_t bytes) -> void* {
    void* p = ws + off;
    off += (bytes + 255) & ~(size_t)255;
    return p;
  };
  int*    counts     = (int*)alloc(NEXP * 4);
  int*    cursor     = (int*)alloc(NEXP * 4);
  int*    offsets    = (int*)alloc(NEXP * 4);
  int*    top_idx    = (int*)alloc((size_t)T_TOK * 4);
  float2* top_w      = (float2*)alloc((size_t)T_TOK * 8);
  int*    list_token = (int*)alloc((size_t)LIST_CAP * 4);
  float*  list_w     = (float*)alloc((size_t)LIST_CAP * 4);
  int2*   rows       = (int2*)alloc((size_t)T_TOK * 8);
  _Float16* xh   = (_Float16*)alloc((size_t)T_TOK * EMB_D * 2);
  _Float16* wg_t = (_Float16*)alloc((size_t)NEXP * HID_D * EMB_D * 2);
  _Float16* wu_t = (_Float16*)alloc((size_t)NEXP * HID_D * EMB_D * 2);
  _Float16* wd_t = (_Float16*)alloc((size_t)NEXP * EMB_D * HID_D * 2);
  _Float16* h    = (_Float16*)alloc((size_t)LIST_CAP * HID_D * 2);
  // y aliased onto xh+wg_t+wu_t (dead after gemm1): needs LIST_CAP*EMB_D*2
  // = 68.2 MB; region is 100.7 MB. gemm2 reads only h/wd_t/list_w.
  _Float16* y = xh;

  hipMemsetAsync(counts, 0, NEXP * 4, stream);

  router_kernel<<<T_TOK / 4, 256, 0, stream>>>(x, rw, xh, top_idx, top_w, counts);
  transpose_cvt<<<dim3(HID_D / 32, EMB_D / 32, NEXP), 256, 0, stream>>>(wg, wg_t, EMB_D, HID_D);
  transpose_cvt<<<dim3(HID_D / 32, EMB_D / 32, NEXP), 256, 0, stream>>>(wu, wu_t, EMB_D, HID_D);
  transpose_cvt<<<dim3(EMB_D / 32, HID_D / 32, NEXP), 256, 0, stream>>>(wd, wd_t, HID_D, EMB_D);
  scan_kernel<<<1, 64, 0, stream>>>(counts, offsets, cursor);
  build_kernel<<<T_TOK / 256, 256, 0, stream>>>(top_idx, top_w, offsets, cursor,
                                                list_token, list_w, rows);
  gemm1_kernel<<<dim3(HID_D / 64, T_TOK / 256, NEXP), 512, 0, stream>>>(
      xh, wg_t, wu_t, counts, offsets, list_token, h);
  gemm2_kernel<<<dim3(EMB_D / 128, T_TOK / 256, NEXP), 512, 0, stream>>>(
      h, wd_t, counts, offsets, list_w, y);
  combine_kernel<<<T_TOK * 128 / 256, 256, 0, stream>>>(y, rows, out);
}

// Round 2
// 1332.298 us; speedup vs baseline: 1.0546x; 1.0546x over previous
//
#include <hip/hip_runtime.h>
#include <hip/hip_fp16.h>

// MoE top-2, T=16384 tokens, D=1024, H=2048, E=8. All inputs fp32.
// Pipeline: router(top2+x->f16) -> scan -> build lists (LDS-rank atomics) ->
// transpose-cvt weights -> grouped GEMM1 (gate+up fused, SiLU) ->
// grouped GEMM2 (down, scaled f16 row store) -> combine (out = y[r0]+y[r1]).
// Internal compute f16 MFMA (16x16x32), fp32 accumulate. Router kept fp32.
// R4: removed per-phase barrier lockstep (R3 post-mortem: LDS drain and MFMA
// bursts alternated, 2030cyc/phase vs 621 matrix). Now: ONE raw s_barrier per
// K-tile, dbuf LDS, stage(t+1) issued at tile start so vmcnt(0) at tile end
// waits on ~2300-cycle-old loads (no bubble). Per-wave tiles enlarged to
// 128x32-dual (gemm1) / 128x64 (gemm2) -> 0.375 KB LDS-read per MFMA.
// build_kernel: LDS-rank scheme, 8 global atomics/block instead of 512.

#define T_TOK 16384
#define EMB_D 1024
#define HID_D 2048
#define NEXP  8
#define LIST_CAP (2 * T_TOK + 256)

typedef _Float16 f16x8 __attribute__((ext_vector_type(8)));
typedef float    f32x4 __attribute__((ext_vector_type(4)));

// async global->LDS, 16B per lane, lane i lands at ldsbase + i*16B
#define GLD16(gp, lp)                                                          \
  __builtin_amdgcn_global_load_lds(                                            \
      (__attribute__((address_space(1))) void*)(void*)(gp),                    \
      (__attribute__((address_space(3))) void*)(lp), 16, 0, 0)

#define VMW0()  asm volatile("s_waitcnt vmcnt(0)" ::: "memory")
#define LGKM0() asm volatile("s_waitcnt lgkmcnt(0)" ::: "memory")

// ---------------------------------------------------------------- router ----
__global__ __launch_bounds__(256) void router_kernel(
    const float* __restrict__ x, const float* __restrict__ rw,
    _Float16* __restrict__ xh, int* __restrict__ top_idx,
    float2* __restrict__ top_w, int* __restrict__ counts) {
  int wave = threadIdx.x >> 6, lane = threadIdx.x & 63;
  int t = blockIdx.x * 4 + wave;              // one wave per token
  const float* xr = x + (size_t)t * EMB_D;
  int d0 = lane * 16;

  float xv[16];
#pragma unroll
  for (int j = 0; j < 4; j++) {
    float4 v = *(const float4*)(xr + d0 + j * 4);
    xv[j * 4 + 0] = v.x; xv[j * 4 + 1] = v.y;
    xv[j * 4 + 2] = v.z; xv[j * 4 + 3] = v.w;
  }
  // fused fp32 -> f16 conversion of x
  _Float16 hx[16];
#pragma unroll
  for (int j = 0; j < 16; j++) hx[j] = (_Float16)xv[j];
  *(f16x8*)(xh + (size_t)t * EMB_D + d0)     = *(f16x8*)(hx);
  *(f16x8*)(xh + (size_t)t * EMB_D + d0 + 8) = *(f16x8*)(hx + 8);

  // logits in fp32 (selection must be exact-ish)
  float acc[NEXP];
#pragma unroll
  for (int e = 0; e < NEXP; e++) acc[e] = 0.f;
#pragma unroll
  for (int j = 0; j < 16; j++) {
    const float* wr = rw + (size_t)(d0 + j) * NEXP;
    float4 wa = *(const float4*)(wr);
    float4 wb = *(const float4*)(wr + 4);
    float xj = xv[j];
    acc[0] += xj * wa.x; acc[1] += xj * wa.y; acc[2] += xj * wa.z; acc[3] += xj * wa.w;
    acc[4] += xj * wb.x; acc[5] += xj * wb.y; acc[6] += xj * wb.z; acc[7] += xj * wb.w;
  }
#pragma unroll
  for (int off = 32; off > 0; off >>= 1)
#pragma unroll
    for (int e = 0; e < NEXP; e++) acc[e] += __shfl_xor(acc[e], off, 64);

  if (lane == 0) {
    int i0 = 0; float v0 = acc[0];
#pragma unroll
    for (int e = 1; e < NEXP; e++) if (acc[e] > v0) { v0 = acc[e]; i0 = e; }
    int i1 = (i0 == 0) ? 1 : 0; float v1 = acc[i1];
#pragma unroll
    for (int e = 0; e < NEXP; e++)
      if (e != i0 && acc[e] > v1) { v1 = acc[e]; i1 = e; }
    float p = __expf(v1 - v0);          // v1 <= v0
    float inv = 1.f / (1.f + p);
    top_idx[t] = i0 | (i1 << 16);
    top_w[t] = make_float2(inv, p * inv);
    atomicAdd(&counts[i0], 1);
    atomicAdd(&counts[i1], 1);
  }
}

// ------------------------------------------------------------------ scan ----
__global__ void scan_kernel(const int* __restrict__ counts,
                            int* __restrict__ offsets, int* __restrict__ cursor) {
  if (threadIdx.x == 0) {
    int s = 0;
    for (int e = 0; e < NEXP; e++) { offsets[e] = s; s += counts[e]; }
  }
  if (threadIdx.x < NEXP) cursor[threadIdx.x] = 0;
}

// ----------------------------------------------------------------- build ----
// LDS-rank scheme: per-block LDS histogram + one global atomic per expert per
// block (8 instead of 512) -> kills cursor atomic contention.
__global__ __launch_bounds__(256) void build_kernel(
    const int* __restrict__ top_idx, const float2* __restrict__ top_w,
    const int* __restrict__ offsets, int* cursor,
    int* __restrict__ list_token, float* __restrict__ list_w,
    int2* __restrict__ rows) {
  __shared__ int cnt[NEXP];
  __shared__ int basee[NEXP];
  int t = blockIdx.x * 256 + threadIdx.x;
  if (threadIdx.x < NEXP) cnt[threadIdx.x] = 0;
  __syncthreads();
  int pk = top_idx[t];
  float2 w = top_w[t];
  int e0 = pk & 0xffff, e1 = pk >> 16;
  int loc0 = atomicAdd(&cnt[e0], 1);
  int loc1 = atomicAdd(&cnt[e1], 1);
  __syncthreads();
  if (threadIdx.x < NEXP)
    basee[threadIdx.x] = atomicAdd(&cursor[threadIdx.x], cnt[threadIdx.x]);
  __syncthreads();
  int r0 = offsets[e0] + basee[e0] + loc0;
  list_token[r0] = t; list_w[r0] = w.x;
  int r1 = offsets[e1] + basee[e1] + loc1;
  list_token[r1] = t; list_w[r1] = w.y;
  rows[t] = make_int2(r0, r1);
}

// ---------------------------------------------------- weight transpose ------
// src fp32 [mat][R][C] -> dst f16 [mat][C][R]   (B^T layout for the GEMMs)
__global__ __launch_bounds__(256) void transpose_cvt(
    const float* __restrict__ src, _Float16* __restrict__ dst, int R, int C) {
  __shared__ float tile[32][33];
  size_t mb = (size_t)blockIdx.z * R * C;
  src += mb; dst += mb;
  int c0 = blockIdx.x * 32, r0 = blockIdx.y * 32;
  int tx = threadIdx.x & 31, ty = threadIdx.x >> 5;   // ty: 0..7
#pragma unroll
  for (int j = 0; j < 4; j++)
    tile[ty + j * 8][tx] = src[(size_t)(r0 + ty + j * 8) * C + c0 + tx];
  __syncthreads();
#pragma unroll
  for (int j = 0; j < 4; j++)
    dst[(size_t)(c0 + ty + j * 8) * R + r0 + tx] = (_Float16)tile[tx][ty + j * 8];
}

// ----------------------------------------------------------------- GEMM1 ----
// per expert: h = silu(X Wg) * (X Wu), X gathered rows of xh.
// 8 waves. tile M=256 x N=128 (dual g+u) x BK=64. Per-wave 128x32-dual:
// af[8] x {bg[2],bu[2]} -> 64 MFMA / 24 ds_read per tile (0.375 KB/MFMA).
// Dbuf LDS (128KB). ONE raw s_barrier per tile; no per-phase lockstep.
// stage(t+1) issued at tile start; vmcnt(0) at tile end waits ~1-tile-old
// loads (latency covered). LDS XOR swizzle: chunk c of row r at phys c^(r&7).
__global__ __launch_bounds__(512) void gemm1_kernel(
    const _Float16* __restrict__ xh, const _Float16* __restrict__ wg_t,
    const _Float16* __restrict__ wu_t, const int* __restrict__ counts,
    const int* __restrict__ offsets, const int* __restrict__ list_token,
    _Float16* __restrict__ h) {
  int e = blockIdx.z;
  int Ne = counts[e];
  int m0 = blockIdx.y * 256;
  if (m0 >= Ne) return;
  int n0 = blockIdx.x * 128;
  int base = offsets[e];

  __shared__ _Float16 lds_a[2][256 * 64];   // 64 KB
  __shared__ _Float16 lds_bg[2][128 * 64];  // 32 KB
  __shared__ _Float16 lds_bu[2][128 * 64];  // 32 KB

  int wave = threadIdx.x >> 6, lane = threadIdx.x & 63;
  int lsub = lane >> 3;                 // row within 8-row group
  int chunk = (lane & 7) ^ lsub;        // logical chunk this lane fetches

  const _Float16* ap[4];
#pragma unroll
  for (int j = 0; j < 4; j++) {
    int lr = j * 64 + wave * 8 + lsub;
    int gidx = base + m0 + lr;
    gidx = min(gidx, 2 * T_TOK - 1);                  // pad-row clamp
    int tok = list_token[gidx] & (T_TOK - 1);         // safety mask
    ap[j] = xh + (size_t)tok * EMB_D + chunk * 8;
  }
  const _Float16* bgp[2]; const _Float16* bup[2];
#pragma unroll
  for (int j = 0; j < 2; j++) {
    int nr = n0 + j * 64 + wave * 8 + lsub;
    bgp[j] = wg_t + ((size_t)e * HID_D + nr) * EMB_D + chunk * 8;
    bup[j] = wu_t + ((size_t)e * HID_D + nr) * EMB_D + chunk * 8;
  }

  auto stage = [&](int t, int b) {
#pragma unroll
    for (int j = 0; j < 4; j++)
      GLD16(ap[j] + t * 64, &lds_a[b][(j * 64 + wave * 8) * 64]);
#pragma unroll
    for (int j = 0; j < 2; j++) {
      GLD16(bgp[j] + t * 64, &lds_bg[b][(j * 64 + wave * 8) * 64]);
      GLD16(bup[j] + t * 64, &lds_bu[b][(j * 64 + wave * 8) * 64]);
    }
  };

  f32x4 accg[8][2], accu[8][2];
#pragma unroll
  for (int im = 0; im < 8; im++)
#pragma unroll
    for (int in = 0; in < 2; in++) {
      accg[im][in] = (f32x4){0.f, 0.f, 0.f, 0.f};
      accu[im][in] = (f32x4){0.f, 0.f, 0.f, 0.f};
    }

  int wm = (wave >> 2) * 128, wn = (wave & 3) * 32;
  int frow = lane & 15, fquad = lane >> 4;
  int r7 = frow & 7;

  stage(0, 0);
  VMW0();
  __builtin_amdgcn_s_barrier();

  int cur = 0;
  for (int t = 0; t < 16; ++t) {
    if (t + 1 < 16) stage(t + 1, cur ^ 1);
#pragma unroll
    for (int ks = 0; ks < 2; ++ks) {
      int c = ks * 4 + fquad;                    // logical chunk
      int sw = ((c ^ r7) << 3);                  // swizzled element offset
      f16x8 bgf[2], bff[2], af[8];
#pragma unroll
      for (int in = 0; in < 2; in++) {
        bgf[in] = *(const f16x8*)&lds_bg[cur][(wn + in * 16 + frow) * 64 + sw];
        bff[in] = *(const f16x8*)&lds_bu[cur][(wn + in * 16 + frow) * 64 + sw];
      }
#pragma unroll
      for (int im = 0; im < 8; im++)
        af[im] = *(const f16x8*)&lds_a[cur][(wm + im * 16 + frow) * 64 + sw];
#pragma unroll
      for (int im = 0; im < 8; im++) {
        accg[im][0] = __builtin_amdgcn_mfma_f32_16x16x32_f16(
            af[im], bgf[0], accg[im][0], 0, 0, 0);
        accg[im][1] = __builtin_amdgcn_mfma_f32_16x16x32_f16(
            af[im], bgf[1], accg[im][1], 0, 0, 0);
        accu[im][0] = __builtin_amdgcn_mfma_f32_16x16x32_f16(
            af[im], bff[0], accu[im][0], 0, 0, 0);
        accu[im][1] = __builtin_amdgcn_mfma_f32_16x16x32_f16(
            af[im], bff[1], accu[im][1], 0, 0, 0);
      }
    }
    VMW0();      // my stage(t+1) loads done (issued one full tile ago)
    LGKM0();     // my ds_reads done -> safe for others to overwrite after bar
    __builtin_amdgcn_s_barrier();
    cur ^= 1;
  }

#pragma unroll
  for (int im = 0; im < 8; im++)
#pragma unroll
    for (int in = 0; in < 2; in++)
#pragma unroll
      for (int r = 0; r < 4; r++) {
        int lm = m0 + wm + im * 16 + fquad * 4 + r;
        if (lm < Ne) {
          int col = n0 + wn + in * 16 + frow;
          float g = accg[im][in][r], u = accu[im][in][r];
          float hv = (g / (1.f + __expf(-g))) * u;    // silu(g)*u
          h[(size_t)(base + lm) * HID_D + col] = (_Float16)hv;
        }
      }
}

// ----------------------------------------------------------------- GEMM2 ----
// y[list_row] = w * (h_row @ Wd)  (f16 store; no atomics).
// 8 waves. tile 256x256, BK=64. Per-wave 128x64: af[8] x bf[4].
// Same dbuf + single-raw-barrier-per-tile schedule as gemm1.
__global__ __launch_bounds__(512) void gemm2_kernel(
    const _Float16* __restrict__ h, const _Float16* __restrict__ wd_t,
    const int* __restrict__ counts, const int* __restrict__ offsets,
    const float* __restrict__ list_w, _Float16* __restrict__ y) {
  int e = blockIdx.z;
  int Ne = counts[e];
  int m0 = blockIdx.y * 256;
  if (m0 >= Ne) return;
  int n0 = blockIdx.x * 256;
  int base = offsets[e];

  __shared__ _Float16 lds_a[2][256 * 64];   // 64 KB
  __shared__ _Float16 lds_b[2][256 * 64];   // 64 KB

  int wave = threadIdx.x >> 6, lane = threadIdx.x & 63;
  int lsub = lane >> 3;
  int chunk = (lane & 7) ^ lsub;

  const _Float16* ap[4]; const _Float16* bp[4];
#pragma unroll
  for (int j = 0; j < 4; j++) {
    int lr = j * 64 + wave * 8 + lsub;
    ap[j] = h + (size_t)(base + m0 + lr) * HID_D + chunk * 8;  // LIST_CAP slack covers pad
    bp[j] = wd_t + ((size_t)e * EMB_D + n0 + lr) * HID_D + chunk * 8;
  }

  auto stage = [&](int t, int b) {
#pragma unroll
    for (int j = 0; j < 4; j++)
      GLD16(ap[j] + t * 64, &lds_a[b][(j * 64 + wave * 8) * 64]);
#pragma unroll
    for (int j = 0; j < 4; j++)
      GLD16(bp[j] + t * 64, &lds_b[b][(j * 64 + wave * 8) * 64]);
  };

  f32x4 acc[8][4];
#pragma unroll
  for (int im = 0; im < 8; im++)
#pragma unroll
    for (int in = 0; in < 4; in++) acc[im][in] = (f32x4){0.f, 0.f, 0.f, 0.f};

  int wm = (wave >> 2) * 128, wn = (wave & 3) * 64;
  int frow = lane & 15, fquad = lane >> 4;
  int r7 = frow & 7;

  stage(0, 0);
  VMW0();
  __builtin_amdgcn_s_barrier();

  int cur = 0;
  for (int t = 0; t < 32; ++t) {
    if (t + 1 < 32) stage(t + 1, cur ^ 1);
#pragma unroll
    for (int ks = 0; ks < 2; ++ks) {
      int c = ks * 4 + fquad;
      int sw = ((c ^ r7) << 3);
      f16x8 bf[4], af[8];
#pragma unroll
      for (int in = 0; in < 4; in++)
        bf[in] = *(const f16x8*)&lds_b[cur][(wn + in * 16 + frow) * 64 + sw];
#pragma unroll
      for (int im = 0; im < 8; im++)
        af[im] = *(const f16x8*)&lds_a[cur][(wm + im * 16 + frow) * 64 + sw];
#pragma unroll
      for (int im = 0; im < 8; im++)
#pragma unroll
        for (int in = 0; in < 4; in++)
          acc[im][in] = __builtin_amdgcn_mfma_f32_16x16x32_f16(
              af[im], bf[in], acc[im][in], 0, 0, 0);
    }
    VMW0();
    LGKM0();
    __builtin_amdgcn_s_barrier();
    cur ^= 1;
  }

#pragma unroll
  for (int im = 0; im < 8; im++)
#pragma unroll
    for (int r = 0; r < 4; r++) {
      int lm = m0 + wm + im * 16 + fquad * 4 + r;
      if (lm < Ne) {
        int gi = base + lm;
        float w = list_w[gi];
#pragma unroll
        for (int in = 0; in < 4; in++) {
          int col = n0 + wn + in * 16 + frow;
          y[(size_t)gi * EMB_D + col] = (_Float16)(acc[im][in][r] * w);
        }
      }
    }
}

// --------------------------------------------------------------- combine ----
// out[t] = y[r0(t)] + y[r1(t)]   (fp32 out; y rows already weight-scaled)
__global__ __launch_bounds__(256) void combine_kernel(
    const _Float16* __restrict__ y, const int2* __restrict__ rows,
    float* __restrict__ out) {
  int tid = blockIdx.x * 256 + threadIdx.x;   // T*128 threads, 8 elems each
  int t = tid >> 7;
  int d0 = (tid & 127) * 8;
  int2 r = rows[t];
  f16x8 a = *(const f16x8*)(y + (size_t)r.x * EMB_D + d0);
  f16x8 b = *(const f16x8*)(y + (size_t)r.y * EMB_D + d0);
  float o[8];
#pragma unroll
  for (int j = 0; j < 8; j++) o[j] = (float)a[j] + (float)b[j];
  float* op = out + (size_t)t * EMB_D + d0;
  *(float4*)(op)     = make_float4(o[0], o[1], o[2], o[3]);
  *(float4*)(op + 4) = make_float4(o[4], o[5], o[6], o[7]);
}

// ---------------------------------------------------------------- launch ----
extern "C" void kernel_launch(void* const* d_in, const int* in_sizes, int n_in,
                              void* d_out, int out_size, void* d_ws, size_t ws_size,
                              hipStream_t stream) {
  const float* x  = (const float*)d_in[0];
  const float* rw = (const float*)d_in[1];
  const float* wg = (const float*)d_in[2];
  const float* wu = (const float*)d_in[3];
  const float* wd = (const float*)d_in[4];
  float* out = (float*)d_out;

  char* ws = (char*)d_ws;
  size_t off = 0;
  auto alloc = [&](size_t bytes) -> void* {
    void* p = ws + off;
    off += (bytes + 255) & ~(size_t)255;
    return p;
  };
  int*    counts     = (int*)alloc(NEXP * 4);
  int*    cursor     = (int*)alloc(NEXP * 4);
  int*    offsets    = (int*)alloc(NEXP * 4);
  int*    top_idx    = (int*)alloc((size_t)T_TOK * 4);
  float2* top_w      = (float2*)alloc((size_t)T_TOK * 8);
  int*    list_token = (int*)alloc((size_t)LIST_CAP * 4);
  float*  list_w     = (float*)alloc((size_t)LIST_CAP * 4);
  int2*   rows       = (int2*)alloc((size_t)T_TOK * 8);
  _Float16* xh   = (_Float16*)alloc((size_t)T_TOK * EMB_D * 2);
  _Float16* wg_t = (_Float16*)alloc((size_t)NEXP * HID_D * EMB_D * 2);
  _Float16* wu_t = (_Float16*)alloc((size_t)NEXP * HID_D * EMB_D * 2);
  _Float16* wd_t = (_Float16*)alloc((size_t)NEXP * EMB_D * HID_D * 2);
  _Float16* h    = (_Float16*)alloc((size_t)LIST_CAP * HID_D * 2);
  // y aliased onto xh+wg_t+wu_t (dead after gemm1): needs LIST_CAP*EMB_D*2
  // = 68.2 MB; region is 100.7 MB. gemm2 reads only h/wd_t/list_w.
  _Float16* y = xh;

  hipMemsetAsync(counts, 0, NEXP * 4, stream);

  router_kernel<<<T_TOK / 4, 256, 0, stream>>>(x, rw, xh, top_idx, top_w, counts);
  transpose_cvt<<<dim3(HID_D / 32, EMB_D / 32, NEXP), 256, 0, stream>>>(wg, wg_t, EMB_D, HID_D);
  transpose_cvt<<<dim3(HID_D / 32, EMB_D / 32, NEXP), 256, 0, stream>>>(wu, wu_t, EMB_D, HID_D);
  transpose_cvt<<<dim3(EMB_D / 32, HID_D / 32, NEXP), 256, 0, stream>>>(wd, wd_t, HID_D, EMB_D);
  scan_kernel<<<1, 64, 0, stream>>>(counts, offsets, cursor);
  build_kernel<<<T_TOK / 256, 256, 0, stream>>>(top_idx, top_w, offsets, cursor,
                                                list_token, list_w, rows);
  gemm1_kernel<<<dim3(HID_D / 128, T_TOK / 256, NEXP), 512, 0, stream>>>(
      xh, wg_t, wu_t, counts, offsets, list_token, h);
  gemm2_kernel<<<dim3(EMB_D / 256, T_TOK / 256, NEXP), 512, 0, stream>>>(
      h, wd_t, counts, offsets, list_w, y);
  combine_kernel<<<T_TOK * 128 / 256, 256, 0, stream>>>(y, rows, out);
}

// Round 4
// 1246.345 us; speedup vs baseline: 1.1274x; 1.0690x over previous
//
#include <hip/hip_runtime.h>
#include <hip/hip_fp16.h>

// MoE top-2, T=16384 tokens, D=1024, H=2048, E=8. All inputs fp32.
// Pipeline: router(top2+x->f16) -> scan -> build lists (LDS-rank atomics) ->
// transpose-cvt weights -> grouped GEMM1 (gate+up fused, SiLU) ->
// grouped GEMM2 (down, scaled f16 row store) -> combine (out = y[r0]+y[r1]).
// Internal compute f16 MFMA (16x16x32), fp32 accumulate. Router kept fp32.
// R5 (resubmit; R5 bench was GPUAcquisitionTimeout, never ran): gemm1 ported
// to the FAITHFUL m201/m248 4-phase-per-K-tile schedule: per phase {ds-read
// only this phase's subtile || stage ONE half-tile unit -> s_barrier ->
// setprio(1) 16 MFMA setprio(0) -> s_waitcnt vmcnt(4) -> s_barrier}.
// Stage-unit -> read-phase distance is 3-4 phases, so vmcnt(4) never stalls
// in steady state (no drain in the main loop). Tile 15 peeled with
// vmcnt(2)/vmcnt(0). gemm2 and all aux kernels unchanged from R4.

#define T_TOK 16384
#define EMB_D 1024
#define HID_D 2048
#define NEXP  8
#define LIST_CAP (2 * T_TOK + 256)

typedef _Float16 f16x8 __attribute__((ext_vector_type(8)));
typedef float    f32x4 __attribute__((ext_vector_type(4)));

// async global->LDS, 16B per lane, lane i lands at ldsbase + i*16B
#define GLD16(gp, lp)                                                          \
  __builtin_amdgcn_global_load_lds(                                            \
      (__attribute__((address_space(1))) void*)(void*)(gp),                    \
      (__attribute__((address_space(3))) void*)(lp), 16, 0, 0)

#define VMW(N)  asm volatile("s_waitcnt vmcnt(" #N ")" ::: "memory")
#define LGKM0() asm volatile("s_waitcnt lgkmcnt(0)" ::: "memory")

// ---------------------------------------------------------------- router ----
__global__ __launch_bounds__(256) void router_kernel(
    const float* __restrict__ x, const float* __restrict__ rw,
    _Float16* __restrict__ xh, int* __restrict__ top_idx,
    float2* __restrict__ top_w, int* __restrict__ counts) {
  int wave = threadIdx.x >> 6, lane = threadIdx.x & 63;
  int t = blockIdx.x * 4 + wave;              // one wave per token
  const float* xr = x + (size_t)t * EMB_D;
  int d0 = lane * 16;

  float xv[16];
#pragma unroll
  for (int j = 0; j < 4; j++) {
    float4 v = *(const float4*)(xr + d0 + j * 4);
    xv[j * 4 + 0] = v.x; xv[j * 4 + 1] = v.y;
    xv[j * 4 + 2] = v.z; xv[j * 4 + 3] = v.w;
  }
  // fused fp32 -> f16 conversion of x
  _Float16 hx[16];
#pragma unroll
  for (int j = 0; j < 16; j++) hx[j] = (_Float16)xv[j];
  *(f16x8*)(xh + (size_t)t * EMB_D + d0)     = *(f16x8*)(hx);
  *(f16x8*)(xh + (size_t)t * EMB_D + d0 + 8) = *(f16x8*)(hx + 8);

  // logits in fp32 (selection must be exact-ish)
  float acc[NEXP];
#pragma unroll
  for (int e = 0; e < NEXP; e++) acc[e] = 0.f;
#pragma unroll
  for (int j = 0; j < 16; j++) {
    const float* wr = rw + (size_t)(d0 + j) * NEXP;
    float4 wa = *(const float4*)(wr);
    float4 wb = *(const float4*)(wr + 4);
    float xj = xv[j];
    acc[0] += xj * wa.x; acc[1] += xj * wa.y; acc[2] += xj * wa.z; acc[3] += xj * wa.w;
    acc[4] += xj * wb.x; acc[5] += xj * wb.y; acc[6] += xj * wb.z; acc[7] += xj * wb.w;
  }
#pragma unroll
  for (int off = 32; off > 0; off >>= 1)
#pragma unroll
    for (int e = 0; e < NEXP; e++) acc[e] += __shfl_xor(acc[e], off, 64);

  if (lane == 0) {
    int i0 = 0; float v0 = acc[0];
#pragma unroll
    for (int e = 1; e < NEXP; e++) if (acc[e] > v0) { v0 = acc[e]; i0 = e; }
    int i1 = (i0 == 0) ? 1 : 0; float v1 = acc[i1];
#pragma unroll
    for (int e = 0; e < NEXP; e++)
      if (e != i0 && acc[e] > v1) { v1 = acc[e]; i1 = e; }
    float p = __expf(v1 - v0);          // v1 <= v0
    float inv = 1.f / (1.f + p);
    top_idx[t] = i0 | (i1 << 16);
    top_w[t] = make_float2(inv, p * inv);
    atomicAdd(&counts[i0], 1);
    atomicAdd(&counts[i1], 1);
  }
}

// ------------------------------------------------------------------ scan ----
__global__ void scan_kernel(const int* __restrict__ counts,
                            int* __restrict__ offsets, int* __restrict__ cursor) {
  if (threadIdx.x == 0) {
    int s = 0;
    for (int e = 0; e < NEXP; e++) { offsets[e] = s; s += counts[e]; }
  }
  if (threadIdx.x < NEXP) cursor[threadIdx.x] = 0;
}

// ----------------------------------------------------------------- build ----
// LDS-rank scheme: per-block LDS histogram + one global atomic per expert per
// block (8 instead of 512) -> kills cursor atomic contention.
__global__ __launch_bounds__(256) void build_kernel(
    const int* __restrict__ top_idx, const float2* __restrict__ top_w,
    const int* __restrict__ offsets, int* cursor,
    int* __restrict__ list_token, float* __restrict__ list_w,
    int2* __restrict__ rows) {
  __shared__ int cnt[NEXP];
  __shared__ int basee[NEXP];
  int t = blockIdx.x * 256 + threadIdx.x;
  if (threadIdx.x < NEXP) cnt[threadIdx.x] = 0;
  __syncthreads();
  int pk = top_idx[t];
  float2 w = top_w[t];
  int e0 = pk & 0xffff, e1 = pk >> 16;
  int loc0 = atomicAdd(&cnt[e0], 1);
  int loc1 = atomicAdd(&cnt[e1], 1);
  __syncthreads();
  if (threadIdx.x < NEXP)
    basee[threadIdx.x] = atomicAdd(&cursor[threadIdx.x], cnt[threadIdx.x]);
  __syncthreads();
  int r0 = offsets[e0] + basee[e0] + loc0;
  list_token[r0] = t; list_w[r0] = w.x;
  int r1 = offsets[e1] + basee[e1] + loc1;
  list_token[r1] = t; list_w[r1] = w.y;
  rows[t] = make_int2(r0, r1);
}

// ---------------------------------------------------- weight transpose ------
// src fp32 [mat][R][C] -> dst f16 [mat][C][R]   (B^T layout for the GEMMs)
__global__ __launch_bounds__(256) void transpose_cvt(
    const float* __restrict__ src, _Float16* __restrict__ dst, int R, int C) {
  __shared__ float tile[32][33];
  size_t mb = (size_t)blockIdx.z * R * C;
  src += mb; dst += mb;
  int c0 = blockIdx.x * 32, r0 = blockIdx.y * 32;
  int tx = threadIdx.x & 31, ty = threadIdx.x >> 5;   // ty: 0..7
#pragma unroll
  for (int j = 0; j < 4; j++)
    tile[ty + j * 8][tx] = src[(size_t)(r0 + ty + j * 8) * C + c0 + tx];
  __syncthreads();
#pragma unroll
  for (int j = 0; j < 4; j++)
    dst[(size_t)(c0 + ty + j * 8) * R + r0 + tx] = (_Float16)tile[tx][ty + j * 8];
}

// ----------------------------------------------------------------- GEMM1 ----
// per expert: h = silu(X Wg) * (X Wu), X gathered rows of xh.
// 8 waves, tile M=256 x N=128(dual) x BK=64, dbuf (128 KB), 1 block/CU.
// Faithful 4-phase schedule per K-tile. Per-wave output 128x32 gate +
// 128x32 up; acc 128 VGPR. Phase p reads only its subtile; stage units:
// P1: A rows {0-63,128-191}(mh0), P2: Bg, P3: Bu, P4: A rows {64-127,
// 192-255}(mh1). Reads: P1 {A-mh0, Bg}, P2 {Bu}, P3 {A-mh1}, P4 {}.
// Distance(stage->read) = 3-4 phases -> vmcnt(4) per phase never stalls.
// LDS XOR swizzle: logical chunk c (8 halves) of row r at phys c^(r&7).
__global__ __launch_bounds__(512, 2) void gemm1_kernel(
    const _Float16* __restrict__ xh, const _Float16* __restrict__ wg_t,
    const _Float16* __restrict__ wu_t, const int* __restrict__ counts,
    const int* __restrict__ offsets, const int* __restrict__ list_token,
    _Float16* __restrict__ h) {
  int e = blockIdx.z;
  int Ne = counts[e];
  int m0 = blockIdx.y * 256;
  if (m0 >= Ne) return;
  int n0 = blockIdx.x * 128;
  int base = offsets[e];

  __shared__ _Float16 lds_a[2][256 * 64];   // 64 KB
  __shared__ _Float16 lds_bg[2][128 * 64];  // 32 KB
  __shared__ _Float16 lds_bu[2][128 * 64];  // 32 KB

  int wave = threadIdx.x >> 6, lane = threadIdx.x & 63;
  int lsub = lane >> 3;                 // row within 8-row group
  int chunk = (lane & 7) ^ lsub;        // logical chunk this lane fetches

  const _Float16* ap[4];
#pragma unroll
  for (int j = 0; j < 4; j++) {
    int lr = j * 64 + wave * 8 + lsub;
    int gidx = base + m0 + lr;
    gidx = min(gidx, 2 * T_TOK - 1);                  // pad-row clamp
    int tok = list_token[gidx] & (T_TOK - 1);         // safety mask
    ap[j] = xh + (size_t)tok * EMB_D + chunk * 8;
  }
  const _Float16* bgp[2]; const _Float16* bup[2];
#pragma unroll
  for (int j = 0; j < 2; j++) {
    int nr = n0 + j * 64 + wave * 8 + lsub;
    bgp[j] = wg_t + ((size_t)e * HID_D + nr) * EMB_D + chunk * 8;
    bup[j] = wu_t + ((size_t)e * HID_D + nr) * EMB_D + chunk * 8;
  }

  // staging units (2 x global_load_lds each)
  auto st_a_mh0 = [&](int t, int b) {
    GLD16(ap[0] + t * 64, &lds_a[b][(0 * 64 + wave * 8) * 64]);
    GLD16(ap[2] + t * 64, &lds_a[b][(2 * 64 + wave * 8) * 64]);
  };
  auto st_a_mh1 = [&](int t, int b) {
    GLD16(ap[1] + t * 64, &lds_a[b][(1 * 64 + wave * 8) * 64]);
    GLD16(ap[3] + t * 64, &lds_a[b][(3 * 64 + wave * 8) * 64]);
  };
  auto st_bg = [&](int t, int b) {
    GLD16(bgp[0] + t * 64, &lds_bg[b][(0 * 64 + wave * 8) * 64]);
    GLD16(bgp[1] + t * 64, &lds_bg[b][(1 * 64 + wave * 8) * 64]);
  };
  auto st_bu = [&](int t, int b) {
    GLD16(bup[0] + t * 64, &lds_bu[b][(0 * 64 + wave * 8) * 64]);
    GLD16(bup[1] + t * 64, &lds_bu[b][(1 * 64 + wave * 8) * 64]);
  };

  f32x4 accg[8][2], accu[8][2];
#pragma unroll
  for (int im = 0; im < 8; im++)
#pragma unroll
    for (int in = 0; in < 2; in++) {
      accg[im][in] = (f32x4){0.f, 0.f, 0.f, 0.f};
      accu[im][in] = (f32x4){0.f, 0.f, 0.f, 0.f};
    }

  int wm = (wave >> 2) * 128, wn = (wave & 3) * 32;
  int frow = lane & 15, fquad = lane >> 4;
  int r7 = frow & 7;

  f16x8 af0[4][2], af1[4][2], bgf[2][2], bff[2][2];

  // fragment-read helpers (compile-time indices after unroll)
#define RD_A(dst, mh, bi)                                                      \
  _Pragma("unroll") for (int im = 0; im < 4; im++)                             \
  _Pragma("unroll") for (int ks = 0; ks < 2; ks++) {                           \
    int rr = wm + (mh) * 64 + im * 16 + frow;                                  \
    int cc = ks * 4 + fquad;                                                   \
    dst[im][ks] = *(const f16x8*)&lds_a[bi][rr * 64 + (((cc) ^ r7) << 3)];     \
  }
#define RD_B(dst, ldsb, bi)                                                    \
  _Pragma("unroll") for (int in = 0; in < 2; in++)                             \
  _Pragma("unroll") for (int ks = 0; ks < 2; ks++) {                           \
    int rr = wn + in * 16 + frow;                                              \
    int cc = ks * 4 + fquad;                                                   \
    dst[in][ks] = *(const f16x8*)&ldsb[bi][rr * 64 + (((cc) ^ r7) << 3)];      \
  }
#define MM16(afr, bfr, acc, mh)                                                \
  __builtin_amdgcn_s_setprio(1);                                               \
  _Pragma("unroll") for (int im = 0; im < 4; im++)                             \
  _Pragma("unroll") for (int in = 0; in < 2; in++)                             \
  _Pragma("unroll") for (int ks = 0; ks < 2; ks++)                             \
    acc[(mh) * 4 + im][in] = __builtin_amdgcn_mfma_f32_16x16x32_f16(           \
        afr[im][ks], bfr[in][ks], acc[(mh) * 4 + im][in], 0, 0, 0);            \
  __builtin_amdgcn_s_setprio(0);

  // prologue: stage tile 0 fully, drain once
  st_a_mh0(0, 0); st_bg(0, 0); st_bu(0, 0); st_a_mh1(0, 0);
  VMW(0);
  __builtin_amdgcn_s_barrier();

  for (int t = 0; t < 15; ++t) {
    int bi = t & 1;
    // ---- P1: read A-mh0 + Bg; stage A-mh0(t+1) ----
    RD_A(af0, 0, bi); RD_B(bgf, lds_bg, bi);
    st_a_mh0(t + 1, bi ^ 1);
    __builtin_amdgcn_s_barrier();
    MM16(af0, bgf, accg, 0);
    VMW(4);
    __builtin_amdgcn_s_barrier();
    // ---- P2: read Bu; stage Bg(t+1) ----
    RD_B(bff, lds_bu, bi);
    st_bg(t + 1, bi ^ 1);
    __builtin_amdgcn_s_barrier();
    MM16(af0, bff, accu, 0);
    VMW(4);
    __builtin_amdgcn_s_barrier();
    // ---- P3: read A-mh1; stage Bu(t+1) ----
    RD_A(af1, 1, bi);
    st_bu(t + 1, bi ^ 1);
    __builtin_amdgcn_s_barrier();
    MM16(af1, bgf, accg, 1);
    VMW(4);
    __builtin_amdgcn_s_barrier();
    // ---- P4: no reads; stage A-mh1(t+1) ----
    st_a_mh1(t + 1, bi ^ 1);
    __builtin_amdgcn_s_barrier();
    MM16(af1, bff, accu, 1);
    VMW(4);
    __builtin_amdgcn_s_barrier();
    __builtin_amdgcn_sched_barrier(0);   // K-tile boundary: no read hoisting
  }
  // ---- peeled tile 15 (no staging; tail waits) ----
  {
    const int bi = 1;
    RD_A(af0, 0, bi); RD_B(bgf, lds_bg, bi);
    __builtin_amdgcn_s_barrier();
    MM16(af0, bgf, accg, 0);
    VMW(2);                              // Bu(15) landed
    __builtin_amdgcn_s_barrier();
    RD_B(bff, lds_bu, bi);
    __builtin_amdgcn_s_barrier();
    MM16(af0, bff, accu, 0);
    VMW(0);                              // A-mh1(15) landed
    __builtin_amdgcn_s_barrier();
    RD_A(af1, 1, bi);
    MM16(af1, bgf, accg, 1);
    MM16(af1, bff, accu, 1);
  }
#undef RD_A
#undef RD_B
#undef MM16

#pragma unroll
  for (int im = 0; im < 8; im++)
#pragma unroll
    for (int in = 0; in < 2; in++)
#pragma unroll
      for (int r = 0; r < 4; r++) {
        int lm = m0 + wm + im * 16 + fquad * 4 + r;
        if (lm < Ne) {
          int col = n0 + wn + in * 16 + frow;
          float g = accg[im][in][r], u = accu[im][in][r];
          float hv = (g / (1.f + __expf(-g))) * u;    // silu(g)*u
          h[(size_t)(base + lm) * HID_D + col] = (_Float16)hv;
        }
      }
}

// ----------------------------------------------------------------- GEMM2 ----
// y[list_row] = w * (h_row @ Wd)  (f16 store; no atomics).
// 8 waves. tile 256x256, BK=64. Per-wave 128x64: af[8] x bf[4].
// Dbuf + single-raw-barrier-per-tile schedule (unchanged from R4).
__global__ __launch_bounds__(512) void gemm2_kernel(
    const _Float16* __restrict__ h, const _Float16* __restrict__ wd_t,
    const int* __restrict__ counts, const int* __restrict__ offsets,
    const float* __restrict__ list_w, _Float16* __restrict__ y) {
  int e = blockIdx.z;
  int Ne = counts[e];
  int m0 = blockIdx.y * 256;
  if (m0 >= Ne) return;
  int n0 = blockIdx.x * 256;
  int base = offsets[e];

  __shared__ _Float16 lds_a[2][256 * 64];   // 64 KB
  __shared__ _Float16 lds_b[2][256 * 64];   // 64 KB

  int wave = threadIdx.x >> 6, lane = threadIdx.x & 63;
  int lsub = lane >> 3;
  int chunk = (lane & 7) ^ lsub;

  const _Float16* ap[4]; const _Float16* bp[4];
#pragma unroll
  for (int j = 0; j < 4; j++) {
    int lr = j * 64 + wave * 8 + lsub;
    ap[j] = h + (size_t)(base + m0 + lr) * HID_D + chunk * 8;  // LIST_CAP slack covers pad
    bp[j] = wd_t + ((size_t)e * EMB_D + n0 + lr) * HID_D + chunk * 8;
  }

  auto stage = [&](int t, int b) {
#pragma unroll
    for (int j = 0; j < 4; j++)
      GLD16(ap[j] + t * 64, &lds_a[b][(j * 64 + wave * 8) * 64]);
#pragma unroll
    for (int j = 0; j < 4; j++)
      GLD16(bp[j] + t * 64, &lds_b[b][(j * 64 + wave * 8) * 64]);
  };

  f32x4 acc[8][4];
#pragma unroll
  for (int im = 0; im < 8; im++)
#pragma unroll
    for (int in = 0; in < 4; in++) acc[im][in] = (f32x4){0.f, 0.f, 0.f, 0.f};

  int wm = (wave >> 2) * 128, wn = (wave & 3) * 64;
  int frow = lane & 15, fquad = lane >> 4;
  int r7 = frow & 7;

  stage(0, 0);
  VMW(0);
  __builtin_amdgcn_s_barrier();

  int cur = 0;
  for (int t = 0; t < 32; ++t) {
    if (t + 1 < 32) stage(t + 1, cur ^ 1);
#pragma unroll
    for (int ks = 0; ks < 2; ++ks) {
      int c = ks * 4 + fquad;
      int sw = ((c ^ r7) << 3);
      f16x8 bf[4], af[8];
#pragma unroll
      for (int in = 0; in < 4; in++)
        bf[in] = *(const f16x8*)&lds_b[cur][(wn + in * 16 + frow) * 64 + sw];
#pragma unroll
      for (int im = 0; im < 8; im++)
        af[im] = *(const f16x8*)&lds_a[cur][(wm + im * 16 + frow) * 64 + sw];
#pragma unroll
      for (int im = 0; im < 8; im++)
#pragma unroll
        for (int in = 0; in < 4; in++)
          acc[im][in] = __builtin_amdgcn_mfma_f32_16x16x32_f16(
              af[im], bf[in], acc[im][in], 0, 0, 0);
    }
    VMW(0);
    LGKM0();
    __builtin_amdgcn_s_barrier();
    cur ^= 1;
  }

#pragma unroll
  for (int im = 0; im < 8; im++)
#pragma unroll
    for (int r = 0; r < 4; r++) {
      int lm = m0 + wm + im * 16 + fquad * 4 + r;
      if (lm < Ne) {
        int gi = base + lm;
        float w = list_w[gi];
#pragma unroll
        for (int in = 0; in < 4; in++) {
          int col = n0 + wn + in * 16 + frow;
          y[(size_t)gi * EMB_D + col] = (_Float16)(acc[im][in][r] * w);
        }
      }
    }
}

// --------------------------------------------------------------- combine ----
// out[t] = y[r0(t)] + y[r1(t)]   (fp32 out; y rows already weight-scaled)
__global__ __launch_bounds__(256) void combine_kernel(
    const _Float16* __restrict__ y, const int2* __restrict__ rows,
    float* __restrict__ out) {
  int tid = blockIdx.x * 256 + threadIdx.x;   // T*128 threads, 8 elems each
  int t = tid >> 7;
  int d0 = (tid & 127) * 8;
  int2 r = rows[t];
  f16x8 a = *(const f16x8*)(y + (size_t)r.x * EMB_D + d0);
  f16x8 b = *(const f16x8*)(y + (size_t)r.y * EMB_D + d0);
  float o[8];
#pragma unroll
  for (int j = 0; j < 8; j++) o[j] = (float)a[j] + (float)b[j];
  float* op = out + (size_t)t * EMB_D + d0;
  *(float4*)(op)     = make_float4(o[0], o[1], o[2], o[3]);
  *(float4*)(op + 4) = make_float4(o[4], o[5], o[6], o[7]);
}

// ---------------------------------------------------------------- launch ----
extern "C" void kernel_launch(void* const* d_in, const int* in_sizes, int n_in,
                              void* d_out, int out_size, void* d_ws, size_t ws_size,
                              hipStream_t stream) {
  const float* x  = (const float*)d_in[0];
  const float* rw = (const float*)d_in[1];
  const float* wg = (const float*)d_in[2];
  const float* wu = (const float*)d_in[3];
  const float* wd = (const float*)d_in[4];
  float* out = (float*)d_out;

  char* ws = (char*)d_ws;
  size_t off = 0;
  auto alloc = [&](size_t bytes) -> void* {
    void* p = ws + off;
    off += (bytes + 255) & ~(size_t)255;
    return p;
  };
  int*    counts     = (int*)alloc(NEXP * 4);
  int*    cursor     = (int*)alloc(NEXP * 4);
  int*    offsets    = (int*)alloc(NEXP * 4);
  int*    top_idx    = (int*)alloc((size_t)T_TOK * 4);
  float2* top_w      = (float2*)alloc((size_t)T_TOK * 8);
  int*    list_token = (int*)alloc((size_t)LIST_CAP * 4);
  float*  list_w     = (float*)alloc((size_t)LIST_CAP * 4);
  int2*   rows       = (int2*)alloc((size_t)T_TOK * 8);
  _Float16* xh   = (_Float16*)alloc((size_t)T_TOK * EMB_D * 2);
  _Float16* wg_t = (_Float16*)alloc((size_t)NEXP * HID_D * EMB_D * 2);
  _Float16* wu_t = (_Float16*)alloc((size_t)NEXP * HID_D * EMB_D * 2);
  _Float16* wd_t = (_Float16*)alloc((size_t)NEXP * EMB_D * HID_D * 2);
  _Float16* h    = (_Float16*)alloc((size_t)LIST_CAP * HID_D * 2);
  // y aliased onto xh+wg_t+wu_t (dead after gemm1): needs LIST_CAP*EMB_D*2
  // = 68.2 MB; region is 100.7 MB. gemm2 reads only h/wd_t/list_w.
  _Float16* y = xh;

  hipMemsetAsync(counts, 0, NEXP * 4, stream);

  router_kernel<<<T_TOK / 4, 256, 0, stream>>>(x, rw, xh, top_idx, top_w, counts);
  transpose_cvt<<<dim3(HID_D / 32, EMB_D / 32, NEXP), 256, 0, stream>>>(wg, wg_t, EMB_D, HID_D);
  transpose_cvt<<<dim3(HID_D / 32, EMB_D / 32, NEXP), 256, 0, stream>>>(wu, wu_t, EMB_D, HID_D);
  transpose_cvt<<<dim3(EMB_D / 32, HID_D / 32, NEXP), 256, 0, stream>>>(wd, wd_t, HID_D, EMB_D);
  scan_kernel<<<1, 64, 0, stream>>>(counts, offsets, cursor);
  build_kernel<<<T_TOK / 256, 256, 0, stream>>>(top_idx, top_w, offsets, cursor,
                                                list_token, list_w, rows);
  gemm1_kernel<<<dim3(HID_D / 128, T_TOK / 256, NEXP), 512, 0, stream>>>(
      xh, wg_t, wu_t, counts, offsets, list_token, h);
  gemm2_kernel<<<dim3(EMB_D / 256, T_TOK / 256, NEXP), 512, 0, stream>>>(
      h, wd_t, counts, offsets, list_w, y);
  combine_kernel<<<T_TOK * 128 / 256, 256, 0, stream>>>(y, rows, out);
}

// Round 5
// 899.276 us; speedup vs baseline: 1.5625x; 1.3859x over previous
//
#include <hip/hip_runtime.h>
#include <hip/hip_fp16.h>

// MoE top-2, T=16384 tokens, D=1024, H=2048, E=8. All inputs fp32.
// Pipeline: router(top2+x->f16, NO atomics) -> hist (ballot, 512 atomics) ->
// scan -> build lists (LDS-rank atomics) -> transpose-cvt weights ->
// grouped GEMM1 (4-phase counted-vmcnt schedule, gate+up fused, SiLU) ->
// grouped GEMM2 (down, scaled f16 row store) -> combine (out = y[r0]+y[r1]).
// Internal compute f16 MFMA (16x16x32), fp32 accumulate. Router kept fp32.
// R6: router was the hidden #1 cost (388us, VALUBusy 1.5%, HBM 2.2% --
// serialized on 32768 contended global atomicAdds to counts[8]). Atomics
// moved to hist_kernel (64 blocks x 8 = 512 atomics); router rewritten with
// coalesced d=j*256+lane*4 layout, 4 tokens/wave, rw reused across tokens.

#define T_TOK 16384
#define EMB_D 1024
#define HID_D 2048
#define NEXP  8
#define LIST_CAP (2 * T_TOK + 256)

typedef _Float16 f16x8 __attribute__((ext_vector_type(8)));
typedef _Float16 f16x4 __attribute__((ext_vector_type(4)));
typedef float    f32x4 __attribute__((ext_vector_type(4)));

// async global->LDS, 16B per lane, lane i lands at ldsbase + i*16B
#define GLD16(gp, lp)                                                          \
  __builtin_amdgcn_global_load_lds(                                            \
      (__attribute__((address_space(1))) void*)(void*)(gp),                    \
      (__attribute__((address_space(3))) void*)(lp), 16, 0, 0)

#define VMW(N)  asm volatile("s_waitcnt vmcnt(" #N ")" ::: "memory")
#define LGKM0() asm volatile("s_waitcnt lgkmcnt(0)" ::: "memory")

// ---------------------------------------------------------------- router ----
// 4 tokens per wave. Lane handles dims d = j*256 + lane*4 + k (k=0..3):
// x loads coalesced (1KB/inst), rw rows 128B-contiguous per lane, reused
// across the wave's 4 tokens. NO global atomics (hist_kernel counts).
__global__ __launch_bounds__(256) void router_kernel(
    const float* __restrict__ x, const float* __restrict__ rw,
    _Float16* __restrict__ xh, int* __restrict__ top_idx,
    float2* __restrict__ top_w) {
  int wave = threadIdx.x >> 6, lane = threadIdx.x & 63;
  int tbase = (blockIdx.x * 4 + wave) * 4;    // 4 tokens per wave

  float acc[4][NEXP];
#pragma unroll
  for (int tok = 0; tok < 4; tok++)
#pragma unroll
    for (int e = 0; e < NEXP; e++) acc[tok][e] = 0.f;

#pragma unroll
  for (int j = 0; j < 4; j++) {
    int d0 = j * 256 + lane * 4;
    const float* wr = rw + (size_t)d0 * NEXP;
    float wrf[4][NEXP];
#pragma unroll
    for (int k = 0; k < 4; k++) {
      float4 a = *(const float4*)(wr + k * NEXP);
      float4 b = *(const float4*)(wr + k * NEXP + 4);
      wrf[k][0] = a.x; wrf[k][1] = a.y; wrf[k][2] = a.z; wrf[k][3] = a.w;
      wrf[k][4] = b.x; wrf[k][5] = b.y; wrf[k][6] = b.z; wrf[k][7] = b.w;
    }
#pragma unroll
    for (int tok = 0; tok < 4; tok++) {
      int t = tbase + tok;
      float4 xv = *(const float4*)(x + (size_t)t * EMB_D + d0);
      float xs[4] = {xv.x, xv.y, xv.z, xv.w};
#pragma unroll
      for (int k = 0; k < 4; k++)
#pragma unroll
        for (int e = 0; e < NEXP; e++) acc[tok][e] += xs[k] * wrf[k][e];
      f16x4 hx;
      hx[0] = (_Float16)xv.x; hx[1] = (_Float16)xv.y;
      hx[2] = (_Float16)xv.z; hx[3] = (_Float16)xv.w;
      *(f16x4*)(xh + (size_t)t * EMB_D + d0) = hx;
    }
  }

#pragma unroll
  for (int off = 32; off > 0; off >>= 1)
#pragma unroll
    for (int tok = 0; tok < 4; tok++)
#pragma unroll
      for (int e = 0; e < NEXP; e++)
        acc[tok][e] += __shfl_xor(acc[tok][e], off, 64);

  if (lane == 0) {
#pragma unroll
    for (int tok = 0; tok < 4; tok++) {
      int t = tbase + tok;
      int i0 = 0; float v0 = acc[tok][0];
#pragma unroll
      for (int e = 1; e < NEXP; e++)
        if (acc[tok][e] > v0) { v0 = acc[tok][e]; i0 = e; }
      int i1 = (i0 == 0) ? 1 : 0; float v1 = acc[tok][i1];
#pragma unroll
      for (int e = 0; e < NEXP; e++)
        if (e != i0 && acc[tok][e] > v1) { v1 = acc[tok][e]; i1 = e; }
      float p = __expf(v1 - v0);        // v1 <= v0
      float inv = 1.f / (1.f + p);
      top_idx[t] = i0 | (i1 << 16);
      top_w[t] = make_float2(inv, p * inv);
    }
  }
}

// ------------------------------------------------------------------ hist ----
// ballot-based per-wave expert counts; 8 global atomics per block (64 blocks).
__global__ __launch_bounds__(256) void hist_kernel(
    const int* __restrict__ top_idx, int* __restrict__ counts) {
  __shared__ int wcnt[4][NEXP];
  int wave = threadIdx.x >> 6, lane = threadIdx.x & 63;
  int t = blockIdx.x * 256 + threadIdx.x;
  int pk = top_idx[t];
  int e0 = pk & 0xffff, e1 = pk >> 16;
#pragma unroll
  for (int e = 0; e < NEXP; e++) {
    unsigned long long m0 = __ballot(e0 == e);
    unsigned long long m1 = __ballot(e1 == e);
    if (lane == 0) wcnt[wave][e] = __popcll(m0) + __popcll(m1);
  }
  __syncthreads();
  if (threadIdx.x < NEXP) {
    int s = wcnt[0][threadIdx.x] + wcnt[1][threadIdx.x] +
            wcnt[2][threadIdx.x] + wcnt[3][threadIdx.x];
    atomicAdd(&counts[threadIdx.x], s);
  }
}

// ------------------------------------------------------------------ scan ----
__global__ void scan_kernel(const int* __restrict__ counts,
                            int* __restrict__ offsets, int* __restrict__ cursor) {
  if (threadIdx.x == 0) {
    int s = 0;
    for (int e = 0; e < NEXP; e++) { offsets[e] = s; s += counts[e]; }
  }
  if (threadIdx.x < NEXP) cursor[threadIdx.x] = 0;
}

// ----------------------------------------------------------------- build ----
// LDS-rank scheme: per-block LDS histogram + one global atomic per expert per
// block (8 instead of 512) -> kills cursor atomic contention.
__global__ __launch_bounds__(256) void build_kernel(
    const int* __restrict__ top_idx, const float2* __restrict__ top_w,
    const int* __restrict__ offsets, int* cursor,
    int* __restrict__ list_token, float* __restrict__ list_w,
    int2* __restrict__ rows) {
  __shared__ int cnt[NEXP];
  __shared__ int basee[NEXP];
  int t = blockIdx.x * 256 + threadIdx.x;
  if (threadIdx.x < NEXP) cnt[threadIdx.x] = 0;
  __syncthreads();
  int pk = top_idx[t];
  float2 w = top_w[t];
  int e0 = pk & 0xffff, e1 = pk >> 16;
  int loc0 = atomicAdd(&cnt[e0], 1);
  int loc1 = atomicAdd(&cnt[e1], 1);
  __syncthreads();
  if (threadIdx.x < NEXP)
    basee[threadIdx.x] = atomicAdd(&cursor[threadIdx.x], cnt[threadIdx.x]);
  __syncthreads();
  int r0 = offsets[e0] + basee[e0] + loc0;
  list_token[r0] = t; list_w[r0] = w.x;
  int r1 = offsets[e1] + basee[e1] + loc1;
  list_token[r1] = t; list_w[r1] = w.y;
  rows[t] = make_int2(r0, r1);
}

// ---------------------------------------------------- weight transpose ------
// src fp32 [mat][R][C] -> dst f16 [mat][C][R]   (B^T layout for the GEMMs)
__global__ __launch_bounds__(256) void transpose_cvt(
    const float* __restrict__ src, _Float16* __restrict__ dst, int R, int C) {
  __shared__ float tile[32][33];
  size_t mb = (size_t)blockIdx.z * R * C;
  src += mb; dst += mb;
  int c0 = blockIdx.x * 32, r0 = blockIdx.y * 32;
  int tx = threadIdx.x & 31, ty = threadIdx.x >> 5;   // ty: 0..7
#pragma unroll
  for (int j = 0; j < 4; j++)
    tile[ty + j * 8][tx] = src[(size_t)(r0 + ty + j * 8) * C + c0 + tx];
  __syncthreads();
#pragma unroll
  for (int j = 0; j < 4; j++)
    dst[(size_t)(c0 + ty + j * 8) * R + r0 + tx] = (_Float16)tile[tx][ty + j * 8];
}

// ----------------------------------------------------------------- GEMM1 ----
// per expert: h = silu(X Wg) * (X Wu), X gathered rows of xh.
// 8 waves, tile M=256 x N=128(dual) x BK=64, dbuf (128 KB), 1 block/CU.
// Faithful 4-phase schedule per K-tile. Per-wave output 128x32 gate +
// 128x32 up; acc 128 VGPR. Phase p reads only its subtile; stage units:
// P1: A rows {0-63,128-191}(mh0), P2: Bg, P3: Bu, P4: A rows {64-127,
// 192-255}(mh1). Reads: P1 {A-mh0, Bg}, P2 {Bu}, P3 {A-mh1}, P4 {}.
// Distance(stage->read) = 3-4 phases -> vmcnt(4) per phase never stalls.
// LDS XOR swizzle: logical chunk c (8 halves) of row r at phys c^(r&7).
__global__ __launch_bounds__(512, 2) void gemm1_kernel(
    const _Float16* __restrict__ xh, const _Float16* __restrict__ wg_t,
    const _Float16* __restrict__ wu_t, const int* __restrict__ counts,
    const int* __restrict__ offsets, const int* __restrict__ list_token,
    _Float16* __restrict__ h) {
  int e = blockIdx.z;
  int Ne = counts[e];
  int m0 = blockIdx.y * 256;
  if (m0 >= Ne) return;
  int n0 = blockIdx.x * 128;
  int base = offsets[e];

  __shared__ _Float16 lds_a[2][256 * 64];   // 64 KB
  __shared__ _Float16 lds_bg[2][128 * 64];  // 32 KB
  __shared__ _Float16 lds_bu[2][128 * 64];  // 32 KB

  int wave = threadIdx.x >> 6, lane = threadIdx.x & 63;
  int lsub = lane >> 3;                 // row within 8-row group
  int chunk = (lane & 7) ^ lsub;        // logical chunk this lane fetches

  const _Float16* ap[4];
#pragma unroll
  for (int j = 0; j < 4; j++) {
    int lr = j * 64 + wave * 8 + lsub;
    int gidx = base + m0 + lr;
    gidx = min(gidx, 2 * T_TOK - 1);                  // pad-row clamp
    int tok = list_token[gidx] & (T_TOK - 1);         // safety mask
    ap[j] = xh + (size_t)tok * EMB_D + chunk * 8;
  }
  const _Float16* bgp[2]; const _Float16* bup[2];
#pragma unroll
  for (int j = 0; j < 2; j++) {
    int nr = n0 + j * 64 + wave * 8 + lsub;
    bgp[j] = wg_t + ((size_t)e * HID_D + nr) * EMB_D + chunk * 8;
    bup[j] = wu_t + ((size_t)e * HID_D + nr) * EMB_D + chunk * 8;
  }

  // staging units (2 x global_load_lds each)
  auto st_a_mh0 = [&](int t, int b) {
    GLD16(ap[0] + t * 64, &lds_a[b][(0 * 64 + wave * 8) * 64]);
    GLD16(ap[2] + t * 64, &lds_a[b][(2 * 64 + wave * 8) * 64]);
  };
  auto st_a_mh1 = [&](int t, int b) {
    GLD16(ap[1] + t * 64, &lds_a[b][(1 * 64 + wave * 8) * 64]);
    GLD16(ap[3] + t * 64, &lds_a[b][(3 * 64 + wave * 8) * 64]);
  };
  auto st_bg = [&](int t, int b) {
    GLD16(bgp[0] + t * 64, &lds_bg[b][(0 * 64 + wave * 8) * 64]);
    GLD16(bgp[1] + t * 64, &lds_bg[b][(1 * 64 + wave * 8) * 64]);
  };
  auto st_bu = [&](int t, int b) {
    GLD16(bup[0] + t * 64, &lds_bu[b][(0 * 64 + wave * 8) * 64]);
    GLD16(bup[1] + t * 64, &lds_bu[b][(1 * 64 + wave * 8) * 64]);
  };

  f32x4 accg[8][2], accu[8][2];
#pragma unroll
  for (int im = 0; im < 8; im++)
#pragma unroll
    for (int in = 0; in < 2; in++) {
      accg[im][in] = (f32x4){0.f, 0.f, 0.f, 0.f};
      accu[im][in] = (f32x4){0.f, 0.f, 0.f, 0.f};
    }

  int wm = (wave >> 2) * 128, wn = (wave & 3) * 32;
  int frow = lane & 15, fquad = lane >> 4;
  int r7 = frow & 7;

  f16x8 af0[4][2], af1[4][2], bgf[2][2], bff[2][2];

  // fragment-read helpers (compile-time indices after unroll)
#define RD_A(dst, mh, bi)                                                      \
  _Pragma("unroll") for (int im = 0; im < 4; im++)                             \
  _Pragma("unroll") for (int ks = 0; ks < 2; ks++) {                           \
    int rr = wm + (mh) * 64 + im * 16 + frow;                                  \
    int cc = ks * 4 + fquad;                                                   \
    dst[im][ks] = *(const f16x8*)&lds_a[bi][rr * 64 + (((cc) ^ r7) << 3)];     \
  }
#define RD_B(dst, ldsb, bi)                                                    \
  _Pragma("unroll") for (int in = 0; in < 2; in++)                             \
  _Pragma("unroll") for (int ks = 0; ks < 2; ks++) {                           \
    int rr = wn + in * 16 + frow;                                              \
    int cc = ks * 4 + fquad;                                                   \
    dst[in][ks] = *(const f16x8*)&ldsb[bi][rr * 64 + (((cc) ^ r7) << 3)];      \
  }
#define MM16(afr, bfr, acc, mh)                                                \
  __builtin_amdgcn_s_setprio(1);                                               \
  _Pragma("unroll") for (int im = 0; im < 4; im++)                             \
  _Pragma("unroll") for (int in = 0; in < 2; in++)                             \
  _Pragma("unroll") for (int ks = 0; ks < 2; ks++)                             \
    acc[(mh) * 4 + im][in] = __builtin_amdgcn_mfma_f32_16x16x32_f16(           \
        afr[im][ks], bfr[in][ks], acc[(mh) * 4 + im][in], 0, 0, 0);            \
  __builtin_amdgcn_s_setprio(0);

  // prologue: stage tile 0 fully, drain once
  st_a_mh0(0, 0); st_bg(0, 0); st_bu(0, 0); st_a_mh1(0, 0);
  VMW(0);
  __builtin_amdgcn_s_barrier();

  for (int t = 0; t < 15; ++t) {
    int bi = t & 1;
    // ---- P1: read A-mh0 + Bg; stage A-mh0(t+1) ----
    RD_A(af0, 0, bi); RD_B(bgf, lds_bg, bi);
    st_a_mh0(t + 1, bi ^ 1);
    __builtin_amdgcn_s_barrier();
    MM16(af0, bgf, accg, 0);
    VMW(4);
    __builtin_amdgcn_s_barrier();
    // ---- P2: read Bu; stage Bg(t+1) ----
    RD_B(bff, lds_bu, bi);
    st_bg(t + 1, bi ^ 1);
    __builtin_amdgcn_s_barrier();
    MM16(af0, bff, accu, 0);
    VMW(4);
    __builtin_amdgcn_s_barrier();
    // ---- P3: read A-mh1; stage Bu(t+1) ----
    RD_A(af1, 1, bi);
    st_bu(t + 1, bi ^ 1);
    __builtin_amdgcn_s_barrier();
    MM16(af1, bgf, accg, 1);
    VMW(4);
    __builtin_amdgcn_s_barrier();
    // ---- P4: no reads; stage A-mh1(t+1) ----
    st_a_mh1(t + 1, bi ^ 1);
    __builtin_amdgcn_s_barrier();
    MM16(af1, bff, accu, 1);
    VMW(4);
    __builtin_amdgcn_s_barrier();
    __builtin_amdgcn_sched_barrier(0);   // K-tile boundary: no read hoisting
  }
  // ---- peeled tile 15 (no staging; tail waits) ----
  {
    const int bi = 1;
    RD_A(af0, 0, bi); RD_B(bgf, lds_bg, bi);
    __builtin_amdgcn_s_barrier();
    MM16(af0, bgf, accg, 0);
    VMW(2);                              // Bu(15) landed
    __builtin_amdgcn_s_barrier();
    RD_B(bff, lds_bu, bi);
    __builtin_amdgcn_s_barrier();
    MM16(af0, bff, accu, 0);
    VMW(0);                              // A-mh1(15) landed
    __builtin_amdgcn_s_barrier();
    RD_A(af1, 1, bi);
    MM16(af1, bgf, accg, 1);
    MM16(af1, bff, accu, 1);
  }
#undef RD_A
#undef RD_B
#undef MM16

#pragma unroll
  for (int im = 0; im < 8; im++)
#pragma unroll
    for (int in = 0; in < 2; in++)
#pragma unroll
      for (int r = 0; r < 4; r++) {
        int lm = m0 + wm + im * 16 + fquad * 4 + r;
        if (lm < Ne) {
          int col = n0 + wn + in * 16 + frow;
          float g = accg[im][in][r], u = accu[im][in][r];
          float hv = (g / (1.f + __expf(-g))) * u;    // silu(g)*u
          h[(size_t)(base + lm) * HID_D + col] = (_Float16)hv;
        }
      }
}

// ----------------------------------------------------------------- GEMM2 ----
// y[list_row] = w * (h_row @ Wd)  (f16 store; no atomics).
// 8 waves. tile 256x256, BK=64. Per-wave 128x64: af[8] x bf[4].
// Dbuf + single-raw-barrier-per-tile schedule (unchanged from R4).
__global__ __launch_bounds__(512) void gemm2_kernel(
    const _Float16* __restrict__ h, const _Float16* __restrict__ wd_t,
    const int* __restrict__ counts, const int* __restrict__ offsets,
    const float* __restrict__ list_w, _Float16* __restrict__ y) {
  int e = blockIdx.z;
  int Ne = counts[e];
  int m0 = blockIdx.y * 256;
  if (m0 >= Ne) return;
  int n0 = blockIdx.x * 256;
  int base = offsets[e];

  __shared__ _Float16 lds_a[2][256 * 64];   // 64 KB
  __shared__ _Float16 lds_b[2][256 * 64];   // 64 KB

  int wave = threadIdx.x >> 6, lane = threadIdx.x & 63;
  int lsub = lane >> 3;
  int chunk = (lane & 7) ^ lsub;

  const _Float16* ap[4]; const _Float16* bp[4];
#pragma unroll
  for (int j = 0; j < 4; j++) {
    int lr = j * 64 + wave * 8 + lsub;
    ap[j] = h + (size_t)(base + m0 + lr) * HID_D + chunk * 8;  // LIST_CAP slack covers pad
    bp[j] = wd_t + ((size_t)e * EMB_D + n0 + lr) * HID_D + chunk * 8;
  }

  auto stage = [&](int t, int b) {
#pragma unroll
    for (int j = 0; j < 4; j++)
      GLD16(ap[j] + t * 64, &lds_a[b][(j * 64 + wave * 8) * 64]);
#pragma unroll
    for (int j = 0; j < 4; j++)
      GLD16(bp[j] + t * 64, &lds_b[b][(j * 64 + wave * 8) * 64]);
  };

  f32x4 acc[8][4];
#pragma unroll
  for (int im = 0; im < 8; im++)
#pragma unroll
    for (int in = 0; in < 4; in++) acc[im][in] = (f32x4){0.f, 0.f, 0.f, 0.f};

  int wm = (wave >> 2) * 128, wn = (wave & 3) * 64;
  int frow = lane & 15, fquad = lane >> 4;
  int r7 = frow & 7;

  stage(0, 0);
  VMW(0);
  __builtin_amdgcn_s_barrier();

  int cur = 0;
  for (int t = 0; t < 32; ++t) {
    if (t + 1 < 32) stage(t + 1, cur ^ 1);
#pragma unroll
    for (int ks = 0; ks < 2; ++ks) {
      int c = ks * 4 + fquad;
      int sw = ((c ^ r7) << 3);
      f16x8 bf[4], af[8];
#pragma unroll
      for (int in = 0; in < 4; in++)
        bf[in] = *(const f16x8*)&lds_b[cur][(wn + in * 16 + frow) * 64 + sw];
#pragma unroll
      for (int im = 0; im < 8; im++)
        af[im] = *(const f16x8*)&lds_a[cur][(wm + im * 16 + frow) * 64 + sw];
#pragma unroll
      for (int im = 0; im < 8; im++)
#pragma unroll
        for (int in = 0; in < 4; in++)
          acc[im][in] = __builtin_amdgcn_mfma_f32_16x16x32_f16(
              af[im], bf[in], acc[im][in], 0, 0, 0);
    }
    VMW(0);
    LGKM0();
    __builtin_amdgcn_s_barrier();
    cur ^= 1;
  }

#pragma unroll
  for (int im = 0; im < 8; im++)
#pragma unroll
    for (int r = 0; r < 4; r++) {
      int lm = m0 + wm + im * 16 + fquad * 4 + r;
      if (lm < Ne) {
        int gi = base + lm;
        float w = list_w[gi];
#pragma unroll
        for (int in = 0; in < 4; in++) {
          int col = n0 + wn + in * 16 + frow;
          y[(size_t)gi * EMB_D + col] = (_Float16)(acc[im][in][r] * w);
        }
      }
    }
}

// --------------------------------------------------------------- combine ----
// out[t] = y[r0(t)] + y[r1(t)]   (fp32 out; y rows already weight-scaled)
__global__ __launch_bounds__(256) void combine_kernel(
    const _Float16* __restrict__ y, const int2* __restrict__ rows,
    float* __restrict__ out) {
  int tid = blockIdx.x * 256 + threadIdx.x;   // T*128 threads, 8 elems each
  int t = tid >> 7;
  int d0 = (tid & 127) * 8;
  int2 r = rows[t];
  f16x8 a = *(const f16x8*)(y + (size_t)r.x * EMB_D + d0);
  f16x8 b = *(const f16x8*)(y + (size_t)r.y * EMB_D + d0);
  float o[8];
#pragma unroll
  for (int j = 0; j < 8; j++) o[j] = (float)a[j] + (float)b[j];
  float* op = out + (size_t)t * EMB_D + d0;
  *(float4*)(op)     = make_float4(o[0], o[1], o[2], o[3]);
  *(float4*)(op + 4) = make_float4(o[4], o[5], o[6], o[7]);
}

// ---------------------------------------------------------------- launch ----
extern "C" void kernel_launch(void* const* d_in, const int* in_sizes, int n_in,
                              void* d_out, int out_size, void* d_ws, size_t ws_size,
                              hipStream_t stream) {
  const float* x  = (const float*)d_in[0];
  const float* rw = (const float*)d_in[1];
  const float* wg = (const float*)d_in[2];
  const float* wu = (const float*)d_in[3];
  const float* wd = (const float*)d_in[4];
  float* out = (float*)d_out;

  char* ws = (char*)d_ws;
  size_t off = 0;
  auto alloc = [&](size_t bytes) -> void* {
    void* p = ws + off;
    off += (bytes + 255) & ~(size_t)255;
    return p;
  };
  int*    counts     = (int*)alloc(NEXP * 4);
  int*    cursor     = (int*)alloc(NEXP * 4);
  int*    offsets    = (int*)alloc(NEXP * 4);
  int*    top_idx    = (int*)alloc((size_t)T_TOK * 4);
  float2* top_w      = (float2*)alloc((size_t)T_TOK * 8);
  int*    list_token = (int*)alloc((size_t)LIST_CAP * 4);
  float*  list_w     = (float*)alloc((size_t)LIST_CAP * 4);
  int2*   rows       = (int2*)alloc((size_t)T_TOK * 8);
  _Float16* xh   = (_Float16*)alloc((size_t)T_TOK * EMB_D * 2);
  _Float16* wg_t = (_Float16*)alloc((size_t)NEXP * HID_D * EMB_D * 2);
  _Float16* wu_t = (_Float16*)alloc((size_t)NEXP * HID_D * EMB_D * 2);
  _Float16* wd_t = (_Float16*)alloc((size_t)NEXP * EMB_D * HID_D * 2);
  _Float16* h    = (_Float16*)alloc((size_t)LIST_CAP * HID_D * 2);
  // y aliased onto xh+wg_t+wu_t (dead after gemm1): needs LIST_CAP*EMB_D*2
  // = 68.2 MB; region is 100.7 MB. gemm2 reads only h/wd_t/list_w.
  _Float16* y = xh;

  hipMemsetAsync(counts, 0, NEXP * 4, stream);

  router_kernel<<<T_TOK / 16, 256, 0, stream>>>(x, rw, xh, top_idx, top_w);
  hist_kernel<<<T_TOK / 256, 256, 0, stream>>>(top_idx, counts);
  transpose_cvt<<<dim3(HID_D / 32, EMB_D / 32, NEXP), 256, 0, stream>>>(wg, wg_t, EMB_D, HID_D);
  transpose_cvt<<<dim3(HID_D / 32, EMB_D / 32, NEXP), 256, 0, stream>>>(wu, wu_t, EMB_D, HID_D);
  transpose_cvt<<<dim3(EMB_D / 32, HID_D / 32, NEXP), 256, 0, stream>>>(wd, wd_t, HID_D, EMB_D);
  scan_kernel<<<1, 64, 0, stream>>>(counts, offsets, cursor);
  build_kernel<<<T_TOK / 256, 256, 0, stream>>>(top_idx, top_w, offsets, cursor,
                                                list_token, list_w, rows);
  gemm1_kernel<<<dim3(HID_D / 128, T_TOK / 256, NEXP), 512, 0, stream>>>(
      xh, wg_t, wu_t, counts, offsets, list_token, h);
  gemm2_kernel<<<dim3(EMB_D / 256, T_TOK / 256, NEXP), 512, 0, stream>>>(
      h, wd_t, counts, offsets, list_w, y);
  combine_kernel<<<T_TOK * 128 / 256, 256, 0, stream>>>(y, rows, out);
}

// Round 7
// 856.481 us; speedup vs baseline: 1.6405x; 1.0500x over previous
//
#include <hip/hip_runtime.h>
#include <hip/hip_fp16.h>

// MoE top-2, T=16384 tokens, D=1024, H=2048, E=8. All inputs fp32.
// Pipeline: router(top2+x->f16, NO atomics) -> hist (ballot, 512 atomics) ->
// scan -> build lists (LDS-rank atomics) -> transpose-cvt weights ->
// grouped GEMM1 (4-phase, gate+up fused, SiLU) ->
// grouped GEMM2 (4-phase, down, scaled f16 row store) -> combine.
// Internal compute f16 MFMA (16x16x32), fp32 accumulate. Router kept fp32.
// R8: R7 failed correctness (absmax 0.13): vmcnt is PER-WAVE -- a wave may
// read LDS rows staged by other waves only if every wave's VMW covering that
// unit precedes a barrier that precedes the read. R7's "VMW(4); read af1"
// violated this. Fix: gemm1 reverted to R6-exact (passed, 383us). gemm2
// ported to 4-phase with invariant-derived waits: stage {Amh0,B01,B23,Amh1},
// VMW(2)@P1-end (publishes Amh1(t) for P2), VMW(2)@P4-end (publishes
// Amh0/B01/B23(t+1) for next P1); peel does VMW(0)+BAR before Amh1 read.

#define T_TOK 16384
#define EMB_D 1024
#define HID_D 2048
#define NEXP  8
#define LIST_CAP (2 * T_TOK + 256)

typedef _Float16 f16x8 __attribute__((ext_vector_type(8)));
typedef _Float16 f16x4 __attribute__((ext_vector_type(4)));
typedef float    f32x4 __attribute__((ext_vector_type(4)));

// async global->LDS, 16B per lane, lane i lands at ldsbase + i*16B
#define GLD16(gp, lp)                                                          \
  __builtin_amdgcn_global_load_lds(                                            \
      (__attribute__((address_space(1))) void*)(void*)(gp),                    \
      (__attribute__((address_space(3))) void*)(lp), 16, 0, 0)

#define VMW(N)  asm volatile("s_waitcnt vmcnt(" #N ")" ::: "memory")
#define BAR()   __builtin_amdgcn_s_barrier()

// ---------------------------------------------------------------- router ----
// 4 tokens per wave. Lane handles dims d = j*256 + lane*4 + k (k=0..3):
// x loads coalesced (1KB/inst), rw rows 128B-contiguous per lane, reused
// across the wave's 4 tokens. NO global atomics (hist_kernel counts).
__global__ __launch_bounds__(256) void router_kernel(
    const float* __restrict__ x, const float* __restrict__ rw,
    _Float16* __restrict__ xh, int* __restrict__ top_idx,
    float2* __restrict__ top_w) {
  int wave = threadIdx.x >> 6, lane = threadIdx.x & 63;
  int tbase = (blockIdx.x * 4 + wave) * 4;    // 4 tokens per wave

  float acc[4][NEXP];
#pragma unroll
  for (int tok = 0; tok < 4; tok++)
#pragma unroll
    for (int e = 0; e < NEXP; e++) acc[tok][e] = 0.f;

#pragma unroll
  for (int j = 0; j < 4; j++) {
    int d0 = j * 256 + lane * 4;
    const float* wr = rw + (size_t)d0 * NEXP;
    float wrf[4][NEXP];
#pragma unroll
    for (int k = 0; k < 4; k++) {
      float4 a = *(const float4*)(wr + k * NEXP);
      float4 b = *(const float4*)(wr + k * NEXP + 4);
      wrf[k][0] = a.x; wrf[k][1] = a.y; wrf[k][2] = a.z; wrf[k][3] = a.w;
      wrf[k][4] = b.x; wrf[k][5] = b.y; wrf[k][6] = b.z; wrf[k][7] = b.w;
    }
#pragma unroll
    for (int tok = 0; tok < 4; tok++) {
      int t = tbase + tok;
      float4 xv = *(const float4*)(x + (size_t)t * EMB_D + d0);
      float xs[4] = {xv.x, xv.y, xv.z, xv.w};
#pragma unroll
      for (int k = 0; k < 4; k++)
#pragma unroll
        for (int e = 0; e < NEXP; e++) acc[tok][e] += xs[k] * wrf[k][e];
      f16x4 hx;
      hx[0] = (_Float16)xv.x; hx[1] = (_Float16)xv.y;
      hx[2] = (_Float16)xv.z; hx[3] = (_Float16)xv.w;
      *(f16x4*)(xh + (size_t)t * EMB_D + d0) = hx;
    }
  }

#pragma unroll
  for (int off = 32; off > 0; off >>= 1)
#pragma unroll
    for (int tok = 0; tok < 4; tok++)
#pragma unroll
      for (int e = 0; e < NEXP; e++)
        acc[tok][e] += __shfl_xor(acc[tok][e], off, 64);

  if (lane == 0) {
#pragma unroll
    for (int tok = 0; tok < 4; tok++) {
      int t = tbase + tok;
      int i0 = 0; float v0 = acc[tok][0];
#pragma unroll
      for (int e = 1; e < NEXP; e++)
        if (acc[tok][e] > v0) { v0 = acc[tok][e]; i0 = e; }
      int i1 = (i0 == 0) ? 1 : 0; float v1 = acc[tok][i1];
#pragma unroll
      for (int e = 0; e < NEXP; e++)
        if (e != i0 && acc[tok][e] > v1) { v1 = acc[tok][e]; i1 = e; }
      float p = __expf(v1 - v0);        // v1 <= v0
      float inv = 1.f / (1.f + p);
      top_idx[t] = i0 | (i1 << 16);
      top_w[t] = make_float2(inv, p * inv);
    }
  }
}

// ------------------------------------------------------------------ hist ----
// ballot-based per-wave expert counts; 8 global atomics per block (64 blocks).
__global__ __launch_bounds__(256) void hist_kernel(
    const int* __restrict__ top_idx, int* __restrict__ counts) {
  __shared__ int wcnt[4][NEXP];
  int wave = threadIdx.x >> 6, lane = threadIdx.x & 63;
  int t = blockIdx.x * 256 + threadIdx.x;
  int pk = top_idx[t];
  int e0 = pk & 0xffff, e1 = pk >> 16;
#pragma unroll
  for (int e = 0; e < NEXP; e++) {
    unsigned long long m0 = __ballot(e0 == e);
    unsigned long long m1 = __ballot(e1 == e);
    if (lane == 0) wcnt[wave][e] = __popcll(m0) + __popcll(m1);
  }
  __syncthreads();
  if (threadIdx.x < NEXP) {
    int s = wcnt[0][threadIdx.x] + wcnt[1][threadIdx.x] +
            wcnt[2][threadIdx.x] + wcnt[3][threadIdx.x];
    atomicAdd(&counts[threadIdx.x], s);
  }
}

// ------------------------------------------------------------------ scan ----
__global__ void scan_kernel(const int* __restrict__ counts,
                            int* __restrict__ offsets, int* __restrict__ cursor) {
  if (threadIdx.x == 0) {
    int s = 0;
    for (int e = 0; e < NEXP; e++) { offsets[e] = s; s += counts[e]; }
  }
  if (threadIdx.x < NEXP) cursor[threadIdx.x] = 0;
}

// ----------------------------------------------------------------- build ----
// LDS-rank scheme: per-block LDS histogram + one global atomic per expert per
// block (8 instead of 512) -> kills cursor atomic contention.
__global__ __launch_bounds__(256) void build_kernel(
    const int* __restrict__ top_idx, const float2* __restrict__ top_w,
    const int* __restrict__ offsets, int* cursor,
    int* __restrict__ list_token, float* __restrict__ list_w,
    int2* __restrict__ rows) {
  __shared__ int cnt[NEXP];
  __shared__ int basee[NEXP];
  int t = blockIdx.x * 256 + threadIdx.x;
  if (threadIdx.x < NEXP) cnt[threadIdx.x] = 0;
  __syncthreads();
  int pk = top_idx[t];
  float2 w = top_w[t];
  int e0 = pk & 0xffff, e1 = pk >> 16;
  int loc0 = atomicAdd(&cnt[e0], 1);
  int loc1 = atomicAdd(&cnt[e1], 1);
  __syncthreads();
  if (threadIdx.x < NEXP)
    basee[threadIdx.x] = atomicAdd(&cursor[threadIdx.x], cnt[threadIdx.x]);
  __syncthreads();
  int r0 = offsets[e0] + basee[e0] + loc0;
  list_token[r0] = t; list_w[r0] = w.x;
  int r1 = offsets[e1] + basee[e1] + loc1;
  list_token[r1] = t; list_w[r1] = w.y;
  rows[t] = make_int2(r0, r1);
}

// ---------------------------------------------------- weight transpose ------
// src fp32 [mat][R][C] -> dst f16 [mat][C][R]   (B^T layout for the GEMMs)
__global__ __launch_bounds__(256) void transpose_cvt(
    const float* __restrict__ src, _Float16* __restrict__ dst, int R, int C) {
  __shared__ float tile[32][33];
  size_t mb = (size_t)blockIdx.z * R * C;
  src += mb; dst += mb;
  int c0 = blockIdx.x * 32, r0 = blockIdx.y * 32;
  int tx = threadIdx.x & 31, ty = threadIdx.x >> 5;   // ty: 0..7
#pragma unroll
  for (int j = 0; j < 4; j++)
    tile[ty + j * 8][tx] = src[(size_t)(r0 + ty + j * 8) * C + c0 + tx];
  __syncthreads();
#pragma unroll
  for (int j = 0; j < 4; j++)
    dst[(size_t)(c0 + ty + j * 8) * R + r0 + tx] = (_Float16)tile[tx][ty + j * 8];
}

// ----------------------------------------------------------------- GEMM1 ----
// per expert: h = silu(X Wg) * (X Wu), X gathered rows of xh.
// 8 waves, tile M=256 x N=128(dual) x BK=64, dbuf (128 KB), 1 block/CU.
// Faithful 4-phase schedule per K-tile (R6-exact; refcheck-passed).
// Phase p reads only its subtile; stage units: P1 A-mh0, P2 Bg, P3 Bu,
// P4 A-mh1. Reads: P1 {A-mh0, Bg}, P2 {Bu}, P3 {A-mh1}, P4 {}.
// Per-phase-end {MFMA; VMW(4); BAR} keeps the wave-local-wait -> barrier ->
// cross-wave-read invariant. Peeled tile 15 with VMW(2)/VMW(0).
// LDS XOR swizzle: logical chunk c (8 halves) of row r at phys c^(r&7).
__global__ __launch_bounds__(512, 2) void gemm1_kernel(
    const _Float16* __restrict__ xh, const _Float16* __restrict__ wg_t,
    const _Float16* __restrict__ wu_t, const int* __restrict__ counts,
    const int* __restrict__ offsets, const int* __restrict__ list_token,
    _Float16* __restrict__ h) {
  int e = blockIdx.z;
  int Ne = counts[e];
  int m0 = blockIdx.y * 256;
  if (m0 >= Ne) return;
  int n0 = blockIdx.x * 128;
  int base = offsets[e];

  __shared__ _Float16 lds_a[2][256 * 64];   // 64 KB
  __shared__ _Float16 lds_bg[2][128 * 64];  // 32 KB
  __shared__ _Float16 lds_bu[2][128 * 64];  // 32 KB

  int wave = threadIdx.x >> 6, lane = threadIdx.x & 63;
  int lsub = lane >> 3;                 // row within 8-row group
  int chunk = (lane & 7) ^ lsub;        // logical chunk this lane fetches

  const _Float16* ap[4];
#pragma unroll
  for (int j = 0; j < 4; j++) {
    int lr = j * 64 + wave * 8 + lsub;
    int gidx = base + m0 + lr;
    gidx = min(gidx, 2 * T_TOK - 1);                  // pad-row clamp
    int tok = list_token[gidx] & (T_TOK - 1);         // safety mask
    ap[j] = xh + (size_t)tok * EMB_D + chunk * 8;
  }
  const _Float16* bgp[2]; const _Float16* bup[2];
#pragma unroll
  for (int j = 0; j < 2; j++) {
    int nr = n0 + j * 64 + wave * 8 + lsub;
    bgp[j] = wg_t + ((size_t)e * HID_D + nr) * EMB_D + chunk * 8;
    bup[j] = wu_t + ((size_t)e * HID_D + nr) * EMB_D + chunk * 8;
  }

  // staging units (2 x global_load_lds each)
  auto st_a_mh0 = [&](int t, int b) {
    GLD16(ap[0] + t * 64, &lds_a[b][(0 * 64 + wave * 8) * 64]);
    GLD16(ap[2] + t * 64, &lds_a[b][(2 * 64 + wave * 8) * 64]);
  };
  auto st_a_mh1 = [&](int t, int b) {
    GLD16(ap[1] + t * 64, &lds_a[b][(1 * 64 + wave * 8) * 64]);
    GLD16(ap[3] + t * 64, &lds_a[b][(3 * 64 + wave * 8) * 64]);
  };
  auto st_bg = [&](int t, int b) {
    GLD16(bgp[0] + t * 64, &lds_bg[b][(0 * 64 + wave * 8) * 64]);
    GLD16(bgp[1] + t * 64, &lds_bg[b][(1 * 64 + wave * 8) * 64]);
  };
  auto st_bu = [&](int t, int b) {
    GLD16(bup[0] + t * 64, &lds_bu[b][(0 * 64 + wave * 8) * 64]);
    GLD16(bup[1] + t * 64, &lds_bu[b][(1 * 64 + wave * 8) * 64]);
  };

  f32x4 accg[8][2], accu[8][2];
#pragma unroll
  for (int im = 0; im < 8; im++)
#pragma unroll
    for (int in = 0; in < 2; in++) {
      accg[im][in] = (f32x4){0.f, 0.f, 0.f, 0.f};
      accu[im][in] = (f32x4){0.f, 0.f, 0.f, 0.f};
    }

  int wm = (wave >> 2) * 128, wn = (wave & 3) * 32;
  int frow = lane & 15, fquad = lane >> 4;
  int r7 = frow & 7;

  f16x8 af0[4][2], af1[4][2], bgf[2][2], bff[2][2];

  // fragment-read helpers (compile-time indices after unroll)
#define RD_A(dst, mh, bi)                                                      \
  _Pragma("unroll") for (int im = 0; im < 4; im++)                             \
  _Pragma("unroll") for (int ks = 0; ks < 2; ks++) {                           \
    int rr = wm + (mh) * 64 + im * 16 + frow;                                  \
    int cc = ks * 4 + fquad;                                                   \
    dst[im][ks] = *(const f16x8*)&lds_a[bi][rr * 64 + (((cc) ^ r7) << 3)];     \
  }
#define RD_B(dst, ldsb, bi)                                                    \
  _Pragma("unroll") for (int in = 0; in < 2; in++)                             \
  _Pragma("unroll") for (int ks = 0; ks < 2; ks++) {                           \
    int rr = wn + in * 16 + frow;                                              \
    int cc = ks * 4 + fquad;                                                   \
    dst[in][ks] = *(const f16x8*)&ldsb[bi][rr * 64 + (((cc) ^ r7) << 3)];      \
  }
#define MM16(afr, bfr, acc, mh)                                                \
  __builtin_amdgcn_s_setprio(1);                                               \
  _Pragma("unroll") for (int im = 0; im < 4; im++)                             \
  _Pragma("unroll") for (int in = 0; in < 2; in++)                             \
  _Pragma("unroll") for (int ks = 0; ks < 2; ks++)                             \
    acc[(mh) * 4 + im][in] = __builtin_amdgcn_mfma_f32_16x16x32_f16(           \
        afr[im][ks], bfr[in][ks], acc[(mh) * 4 + im][in], 0, 0, 0);            \
  __builtin_amdgcn_s_setprio(0);

  // prologue: stage tile 0 fully, drain once
  st_a_mh0(0, 0); st_bg(0, 0); st_bu(0, 0); st_a_mh1(0, 0);
  VMW(0);
  BAR();

  for (int t = 0; t < 15; ++t) {
    int bi = t & 1;
    // ---- P1: read A-mh0 + Bg; stage A-mh0(t+1) ----
    RD_A(af0, 0, bi); RD_B(bgf, lds_bg, bi);
    st_a_mh0(t + 1, bi ^ 1);
    BAR();
    MM16(af0, bgf, accg, 0);
    VMW(4);
    BAR();
    // ---- P2: read Bu; stage Bg(t+1) ----
    RD_B(bff, lds_bu, bi);
    st_bg(t + 1, bi ^ 1);
    BAR();
    MM16(af0, bff, accu, 0);
    VMW(4);
    BAR();
    // ---- P3: read A-mh1; stage Bu(t+1) ----
    RD_A(af1, 1, bi);
    st_bu(t + 1, bi ^ 1);
    BAR();
    MM16(af1, bgf, accg, 1);
    VMW(4);
    BAR();
    // ---- P4: no reads; stage A-mh1(t+1) ----
    st_a_mh1(t + 1, bi ^ 1);
    BAR();
    MM16(af1, bff, accu, 1);
    VMW(4);
    BAR();
    __builtin_amdgcn_sched_barrier(0);   // K-tile boundary: no read hoisting
  }
  // ---- peeled tile 15 (no staging; tail waits) ----
  {
    const int bi = 1;
    RD_A(af0, 0, bi); RD_B(bgf, lds_bg, bi);
    BAR();
    MM16(af0, bgf, accg, 0);
    VMW(2);                              // Bu(15) landed
    BAR();
    RD_B(bff, lds_bu, bi);
    BAR();
    MM16(af0, bff, accu, 0);
    VMW(0);                              // A-mh1(15) landed
    BAR();
    RD_A(af1, 1, bi);
    MM16(af1, bgf, accg, 1);
    MM16(af1, bff, accu, 1);
  }
#undef RD_A
#undef RD_B
#undef MM16

#pragma unroll
  for (int im = 0; im < 8; im++)
#pragma unroll
    for (int in = 0; in < 2; in++)
#pragma unroll
      for (int r = 0; r < 4; r++) {
        int lm = m0 + wm + im * 16 + fquad * 4 + r;
        if (lm < Ne) {
          int col = n0 + wn + in * 16 + frow;
          float g = accg[im][in][r], u = accu[im][in][r];
          float hv = (g / (1.f + __expf(-g))) * u;    // silu(g)*u
          h[(size_t)(base + lm) * HID_D + col] = (_Float16)hv;
        }
      }
}

// ----------------------------------------------------------------- GEMM2 ----
// y[list_row] = w * (h_row @ Wd)  (f16 store; no atomics).
// 8 waves, tile 256x256, BK=64, dbuf (128 KB). 4 phases/tile by (mh,ks):
// P1(mh0,ks0) P2(mh1,ks0) P3(mh0,ks1) P4(mh1,ks1), 16 MFMA each, reads
// 8/4/8/4. Stage order {Amh0, B01, B23, Amh1}. Invariant-derived waits:
// VMW(2)@P1-end publishes Amh1(t) (read P2/P4 from bi); VMW(2)@P4-end
// publishes Amh0/B01/B23(t+1) (read next P1). Fragments re-read per ks
// phase so live regs stay ~210. Peel: VMW(0)+BAR before Amh1 read.
__global__ __launch_bounds__(512, 2) void gemm2_kernel(
    const _Float16* __restrict__ h, const _Float16* __restrict__ wd_t,
    const int* __restrict__ counts, const int* __restrict__ offsets,
    const float* __restrict__ list_w, _Float16* __restrict__ y) {
  int e = blockIdx.z;
  int Ne = counts[e];
  int m0 = blockIdx.y * 256;
  if (m0 >= Ne) return;
  int n0 = blockIdx.x * 256;
  int base = offsets[e];

  __shared__ _Float16 lds_a[2][256 * 64];   // 64 KB
  __shared__ _Float16 lds_b[2][256 * 64];   // 64 KB

  int wave = threadIdx.x >> 6, lane = threadIdx.x & 63;
  int lsub = lane >> 3;
  int chunk = (lane & 7) ^ lsub;

  const _Float16* ap[4]; const _Float16* bp[4];
#pragma unroll
  for (int j = 0; j < 4; j++) {
    int lr = j * 64 + wave * 8 + lsub;
    ap[j] = h + (size_t)(base + m0 + lr) * HID_D + chunk * 8;  // LIST_CAP slack covers pad
    bp[j] = wd_t + ((size_t)e * EMB_D + n0 + lr) * HID_D + chunk * 8;
  }

  auto st_a_mh0 = [&](int t, int b) {
    GLD16(ap[0] + t * 64, &lds_a[b][(0 * 64 + wave * 8) * 64]);
    GLD16(ap[2] + t * 64, &lds_a[b][(2 * 64 + wave * 8) * 64]);
  };
  auto st_a_mh1 = [&](int t, int b) {
    GLD16(ap[1] + t * 64, &lds_a[b][(1 * 64 + wave * 8) * 64]);
    GLD16(ap[3] + t * 64, &lds_a[b][(3 * 64 + wave * 8) * 64]);
  };
  auto st_b01 = [&](int t, int b) {
    GLD16(bp[0] + t * 64, &lds_b[b][(0 * 64 + wave * 8) * 64]);
    GLD16(bp[1] + t * 64, &lds_b[b][(1 * 64 + wave * 8) * 64]);
  };
  auto st_b23 = [&](int t, int b) {
    GLD16(bp[2] + t * 64, &lds_b[b][(2 * 64 + wave * 8) * 64]);
    GLD16(bp[3] + t * 64, &lds_b[b][(3 * 64 + wave * 8) * 64]);
  };

  f32x4 acc[8][4];
#pragma unroll
  for (int im = 0; im < 8; im++)
#pragma unroll
    for (int in = 0; in < 4; in++) acc[im][in] = (f32x4){0.f, 0.f, 0.f, 0.f};

  int wm = (wave >> 2) * 128, wn = (wave & 3) * 64;
  int frow = lane & 15, fquad = lane >> 4;
  int r7 = frow & 7;

  f16x8 af0[4], af1[4], bf[4];          // re-read per ks phase

#define RD_A2(dst, mh, ks, bi)                                                 \
  _Pragma("unroll") for (int im = 0; im < 4; im++) {                           \
    int rr = wm + (mh) * 64 + im * 16 + frow;                                  \
    int cc = (ks) * 4 + fquad;                                                 \
    dst[im] = *(const f16x8*)&lds_a[bi][rr * 64 + (((cc) ^ r7) << 3)];         \
  }
#define RD_B2(ks, bi)                                                          \
  _Pragma("unroll") for (int in = 0; in < 4; in++) {                           \
    int rr = wn + in * 16 + frow;                                              \
    int cc = (ks) * 4 + fquad;                                                 \
    bf[in] = *(const f16x8*)&lds_b[bi][rr * 64 + (((cc) ^ r7) << 3)];          \
  }
#define MM16B(afr, mh)                                                         \
  __builtin_amdgcn_s_setprio(1);                                               \
  _Pragma("unroll") for (int im = 0; im < 4; im++)                             \
  _Pragma("unroll") for (int in = 0; in < 4; in++)                             \
    acc[(mh) * 4 + im][in] = __builtin_amdgcn_mfma_f32_16x16x32_f16(           \
        afr[im], bf[in], acc[(mh) * 4 + im][in], 0, 0, 0);                     \
  __builtin_amdgcn_s_setprio(0);

  // prologue: stage tile 0 fully, drain once
  st_a_mh0(0, 0); st_b01(0, 0); st_b23(0, 0); st_a_mh1(0, 0);
  VMW(0);
  BAR();

  for (int t = 0; t < 31; ++t) {
    int bi = t & 1;
    // ---- P1 (mh0,ks0): reads Amh0/B01/B23(t); stage Amh0(t+1) ----
    RD_A2(af0, 0, 0, bi); RD_B2(0, bi);
    st_a_mh0(t + 1, bi ^ 1);
    BAR();
    MM16B(af0, 0);
    VMW(2);            // completes Amh1(t) in every wave -> published by BAR
    BAR();
    // ---- P2 (mh1,ks0): read Amh1(t); stage B01(t+1) ----
    RD_A2(af1, 1, 0, bi);
    st_b01(t + 1, bi ^ 1);
    BAR();
    MM16B(af1, 1);
    BAR();
    // ---- P3 (mh0,ks1): re-read af0/bf at ks1; stage B23(t+1) ----
    RD_A2(af0, 0, 1, bi); RD_B2(1, bi);
    st_b23(t + 1, bi ^ 1);
    BAR();
    MM16B(af0, 0);
    BAR();
    // ---- P4 (mh1,ks1): read af1 ks1; stage Amh1(t+1) ----
    RD_A2(af1, 1, 1, bi);
    st_a_mh1(t + 1, bi ^ 1);
    BAR();
    MM16B(af1, 1);
    VMW(2);            // completes Amh0/B01/B23(t+1) -> published by BAR
    BAR();
    __builtin_amdgcn_sched_barrier(0);   // K-tile boundary
  }
  // ---- peeled tile 31 (no staging) ----
  {
    const int bi = 1;
    RD_A2(af0, 0, 0, bi); RD_B2(0, bi);
    BAR();
    MM16B(af0, 0);
    VMW(0);                              // Amh1(31) landed (all waves)
    BAR();
    RD_A2(af1, 1, 0, bi);
    MM16B(af1, 1);
    RD_A2(af0, 0, 1, bi); RD_B2(1, bi);
    MM16B(af0, 0);
    RD_A2(af1, 1, 1, bi);
    MM16B(af1, 1);
  }
#undef RD_A2
#undef RD_B2
#undef MM16B

#pragma unroll
  for (int im = 0; im < 8; im++)
#pragma unroll
    for (int r = 0; r < 4; r++) {
      int lm = m0 + wm + im * 16 + fquad * 4 + r;
      if (lm < Ne) {
        int gi = base + lm;
        float w = list_w[gi];
#pragma unroll
        for (int in = 0; in < 4; in++) {
          int col = n0 + wn + in * 16 + frow;
          y[(size_t)gi * EMB_D + col] = (_Float16)(acc[im][in][r] * w);
        }
      }
    }
}

// --------------------------------------------------------------- combine ----
// out[t] = y[r0(t)] + y[r1(t)]   (fp32 out; y rows already weight-scaled)
__global__ __launch_bounds__(256) void combine_kernel(
    const _Float16* __restrict__ y, const int2* __restrict__ rows,
    float* __restrict__ out) {
  int tid = blockIdx.x * 256 + threadIdx.x;   // T*128 threads, 8 elems each
  int t = tid >> 7;
  int d0 = (tid & 127) * 8;
  int2 r = rows[t];
  f16x8 a = *(const f16x8*)(y + (size_t)r.x * EMB_D + d0);
  f16x8 b = *(const f16x8*)(y + (size_t)r.y * EMB_D + d0);
  float o[8];
#pragma unroll
  for (int j = 0; j < 8; j++) o[j] = (float)a[j] + (float)b[j];
  float* op = out + (size_t)t * EMB_D + d0;
  *(float4*)(op)     = make_float4(o[0], o[1], o[2], o[3]);
  *(float4*)(op + 4) = make_float4(o[4], o[5], o[6], o[7]);
}

// ---------------------------------------------------------------- launch ----
extern "C" void kernel_launch(void* const* d_in, const int* in_sizes, int n_in,
                              void* d_out, int out_size, void* d_ws, size_t ws_size,
                              hipStream_t stream) {
  const float* x  = (const float*)d_in[0];
  const float* rw = (const float*)d_in[1];
  const float* wg = (const float*)d_in[2];
  const float* wu = (const float*)d_in[3];
  const float* wd = (const float*)d_in[4];
  float* out = (float*)d_out;

  char* ws = (char*)d_ws;
  size_t off = 0;
  auto alloc = [&](size_t bytes) -> void* {
    void* p = ws + off;
    off += (bytes + 255) & ~(size_t)255;
    return p;
  };
  int*    counts     = (int*)alloc(NEXP * 4);
  int*    cursor     = (int*)alloc(NEXP * 4);
  int*    offsets    = (int*)alloc(NEXP * 4);
  int*    top_idx    = (int*)alloc((size_t)T_TOK * 4);
  float2* top_w      = (float2*)alloc((size_t)T_TOK * 8);
  int*    list_token = (int*)alloc((size_t)LIST_CAP * 4);
  float*  list_w     = (float*)alloc((size_t)LIST_CAP * 4);
  int2*   rows       = (int2*)alloc((size_t)T_TOK * 8);
  _Float16* xh   = (_Float16*)alloc((size_t)T_TOK * EMB_D * 2);
  _Float16* wg_t = (_Float16*)alloc((size_t)NEXP * HID_D * EMB_D * 2);
  _Float16* wu_t = (_Float16*)alloc((size_t)NEXP * HID_D * EMB_D * 2);
  _Float16* wd_t = (_Float16*)alloc((size_t)NEXP * EMB_D * HID_D * 2);
  _Float16* h    = (_Float16*)alloc((size_t)LIST_CAP * HID_D * 2);
  // y aliased onto xh+wg_t+wu_t (dead after gemm1): needs LIST_CAP*EMB_D*2
  // = 68.2 MB; region is 100.7 MB. gemm2 reads only h/wd_t/list_w.
  _Float16* y = xh;

  hipMemsetAsync(counts, 0, NEXP * 4, stream);

  router_kernel<<<T_TOK / 16, 256, 0, stream>>>(x, rw, xh, top_idx, top_w);
  hist_kernel<<<T_TOK / 256, 256, 0, stream>>>(top_idx, counts);
  transpose_cvt<<<dim3(HID_D / 32, EMB_D / 32, NEXP), 256, 0, stream>>>(wg, wg_t, EMB_D, HID_D);
  transpose_cvt<<<dim3(HID_D / 32, EMB_D / 32, NEXP), 256, 0, stream>>>(wu, wu_t, EMB_D, HID_D);
  transpose_cvt<<<dim3(EMB_D / 32, HID_D / 32, NEXP), 256, 0, stream>>>(wd, wd_t, HID_D, EMB_D);
  scan_kernel<<<1, 64, 0, stream>>>(counts, offsets, cursor);
  build_kernel<<<T_TOK / 256, 256, 0, stream>>>(top_idx, top_w, offsets, cursor,
                                                list_token, list_w, rows);
  gemm1_kernel<<<dim3(HID_D / 128, T_TOK / 256, NEXP), 512, 0, stream>>>(
      xh, wg_t, wu_t, counts, offsets, list_token, h);
  gemm2_kernel<<<dim3(EMB_D / 256, T_TOK / 256, NEXP), 512, 0, stream>>>(
      h, wd_t, counts, offsets, list_w, y);
  combine_kernel<<<T_TOK * 128 / 256, 256, 0, stream>>>(y, rows, out);
}